// Round 1
// baseline (1159.706 us; speedup 1.0000x reference)
//
#include <hip/hip_runtime.h>

typedef short short8 __attribute__((ext_vector_type(8)));
typedef float f32x4 __attribute__((ext_vector_type(4)));

__device__ __forceinline__ unsigned short f2bu(float f) {
  unsigned u = __builtin_bit_cast(unsigned, f);
  u += 0x7fffu + ((u >> 16) & 1u);
  return (unsigned short)(u >> 16);
}

__device__ __forceinline__ float gelu_t(float x) {
  float x3 = x * x * x;
  float t = tanhf(0.7978845608028654f * (x + 0.044715f * x3));
  return 0.5f * x * (1.f + t);
}

// ---------------- small prep: silu(vec), temperature scales ----------------
__global__ __launch_bounds__(256) void prep_small(
    const float* __restrict__ vec, const float* __restrict__ sol_t,
    float* __restrict__ silu_vec, float* __restrict__ scales) {
  __shared__ float red[4];
  int t = threadIdx.x;
  float v = (t < 64) ? sol_t[t] : 0.f;
#pragma unroll
  for (int o = 32; o > 0; o >>= 1) v += __shfl_down(v, o);
  if ((t & 63) == 0) red[t >> 6] = v;
  __syncthreads();
  if (t == 0) {
    float m = (red[0] + red[1] + red[2] + red[3]) * (1.f / 64.f);
    m = fmaxf(m, 0.1f);
    const float sc = 0.08838834764831845f;  // 128^-0.5
    scales[0] = sc;
    scales[1] = sc / m;  // s_eff^2 folded into score scale
  }
  for (int k = t; k < 2048; k += 256) {
    float x = vec[k];
    silu_vec[k] = x / (1.f + expf(-x));
  }
}

// ---------------- bilinear-resized modulation map ----------------
__global__ __launch_bounds__(256) void mod_kernel(
    const float* __restrict__ S, const float* __restrict__ mw,
    const float* __restrict__ mb, float* __restrict__ modb) {
  int idx = blockIdx.x * 256 + threadIdx.x;  // 16*2048
  int h = idx >> 11, n = idx & 2047;
  int y = n >> 5, x = n & 31;
  float cy = (y + 0.5f) * 0.125f - 0.5f;
  float cx = (x + 0.5f) * 0.25f - 0.5f;
  int y0 = (int)floorf(cy); float fy = cy - (float)y0;
  int x0 = (int)floorf(cx); float fx = cx - (float)x0;
  int y0c = min(max(y0, 0), 7), y1c = min(max(y0 + 1, 0), 7);
  int x0c = min(max(x0, 0), 7), x1c = min(max(x0 + 1, 0), 7);
  float v = (1.f - fy) * ((1.f - fx) * S[y0c * 8 + x0c] + fx * S[y0c * 8 + x1c]) +
            fy * ((1.f - fx) * S[y1c * 8 + x0c] + fx * S[y1c * 8 + x1c]);
  float t = v * mw[h] + mb[h];
  t = fminf(fmaxf(t, -2.f), 2.f);
  modb[idx] = expf(t);
}

// ---------------- adaLN GEMV: e = silu(vec) @ W + b ----------------
__global__ __launch_bounds__(256) void ada_gemv(
    const float* __restrict__ sv,
    const float* __restrict__ Wi, const float* __restrict__ bi,
    const float* __restrict__ Wt, const float* __restrict__ bt,
    float* __restrict__ ei, float* __restrict__ et) {
  __shared__ float red[4][64];
  const float* W = blockIdx.y ? Wt : Wi;
  const float* bb = blockIdx.y ? bt : bi;
  float* e = blockIdx.y ? et : ei;
  int jl = threadIdx.x & 63, ks = threadIdx.x >> 6;
  int j = blockIdx.x * 64 + jl;
  float acc = 0.f;
  int k0 = ks * 512;
#pragma unroll 4
  for (int k = 0; k < 512; ++k) acc += sv[k0 + k] * W[(size_t)(k0 + k) * 12288 + j];
  red[ks][jl] = acc;
  __syncthreads();
  if (ks == 0) e[j] = red[0][jl] + red[1][jl] + red[2][jl] + red[3][jl] + bb[j];
}

// ---------------- RMSNorm + adaLN modulate -> bf16 ----------------
__global__ __launch_bounds__(256) void rmsmod_kernel(
    const float* __restrict__ X, const float* __restrict__ nw,
    const float* __restrict__ e, int sh_off, int sc_off,
    unsigned short* __restrict__ out) {
  __shared__ float red[4];
  int r = blockIdx.x, t = threadIdx.x;
  const float4* xr = reinterpret_cast<const float4*>(X + (size_t)r * 2048);
  float4 v0 = xr[t * 2], v1 = xr[t * 2 + 1];
  float ss = v0.x * v0.x + v0.y * v0.y + v0.z * v0.z + v0.w * v0.w +
             v1.x * v1.x + v1.y * v1.y + v1.z * v1.z + v1.w * v1.w;
#pragma unroll
  for (int o = 32; o > 0; o >>= 1) ss += __shfl_down(ss, o);
  if ((t & 63) == 0) red[t >> 6] = ss;
  __syncthreads();
  float rinv = rsqrtf((red[0] + red[1] + red[2] + red[3]) * (1.f / 2048.f) + 1e-6f);
  int c0 = t * 8;
  float xv[8] = {v0.x, v0.y, v0.z, v0.w, v1.x, v1.y, v1.z, v1.w};
  short8 ov;
#pragma unroll
  for (int i = 0; i < 8; ++i) {
    int c = c0 + i;
    float y = xv[i] * rinv * nw[c] * (1.f + e[sc_off + c]) + e[sh_off + c];
    ov[i] = (short)f2bu(y);
  }
  *reinterpret_cast<short8*>(out + (size_t)r * 2048 + c0) = ov;
}

// ---------------- weight transpose+convert: f32 [K][N] -> bf16 [N][K] ----------------
__global__ __launch_bounds__(256) void transpose_w(
    const float* __restrict__ W, unsigned short* __restrict__ Bt, int K, int N) {
  __shared__ float tile[32][33];
  int n0 = blockIdx.x * 32, k0 = blockIdx.y * 32;
  int tx = threadIdx.x, ty = threadIdx.y;
#pragma unroll
  for (int j = 0; j < 32; j += 8)
    tile[ty + j][tx] = W[(size_t)(k0 + ty + j) * N + n0 + tx];
  __syncthreads();
#pragma unroll
  for (int j = 0; j < 32; j += 8)
    Bt[(size_t)(n0 + ty + j) * K + k0 + tx] = f2bu(tile[tx][ty + j]);
}

// ---------------- bf16 transpose for V: [16][2560][128] -> [16][128][2560] ----------------
__global__ __launch_bounds__(256) void transpose_v(
    const unsigned short* __restrict__ V, unsigned short* __restrict__ Vt) {
  __shared__ unsigned short tile[32][33];
  int h = blockIdx.z;
  int s0 = blockIdx.x * 32, d0 = blockIdx.y * 32;
  int tx = threadIdx.x, ty = threadIdx.y;
  const unsigned short* src = V + (size_t)h * 2560 * 128;
  unsigned short* dst = Vt + (size_t)h * 128 * 2560;
#pragma unroll
  for (int j = 0; j < 32; j += 8)
    tile[ty + j][tx] = src[(size_t)(s0 + ty + j) * 128 + d0 + tx];
  __syncthreads();
#pragma unroll
  for (int j = 0; j < 32; j += 8)
    dst[(size_t)(d0 + ty + j) * 2560 + s0 + tx] = tile[tx][ty + j];
}

// ---------------- GEMM: C[M][N] = A(bf16 [M][K]) * Bt(bf16 [N][K])^T ----------------
__global__ __launch_bounds__(256) void gemm_kernel(
    const unsigned short* __restrict__ A, const unsigned short* __restrict__ Bt,
    float* __restrict__ C, int M, int N, int K) {
  __shared__ int4 sA[128 * 8];
  __shared__ int4 sB[128 * 8];
  const int tid = threadIdx.x;
  const int m0 = blockIdx.y * 128, n0 = blockIdx.x * 128;
  const int w = tid >> 6, l = tid & 63, lr = l & 15, lg = l >> 4;
  const int wm = (w >> 1) * 64, wn = (w & 1) * 64;
  f32x4 acc[4][4] = {};
  const int4* Ag = reinterpret_cast<const int4*>(A);
  const int4* Bg = reinterpret_cast<const int4*>(Bt);
  const int K8 = K >> 3;
  const short8* pA = reinterpret_cast<const short8*>(sA);
  const short8* pB = reinterpret_cast<const short8*>(sB);
  for (int k0 = 0; k0 < K; k0 += 64) {
    __syncthreads();
    int kc = k0 >> 3;
#pragma unroll
    for (int i = 0; i < 4; ++i) {
      int c = i * 256 + tid;
      int row = c >> 3, ch = c & 7;
      sA[row * 8 + (ch ^ (row & 7))] = Ag[(size_t)(m0 + row) * K8 + kc + ch];
      sB[row * 8 + (ch ^ (row & 7))] = Bg[(size_t)(n0 + row) * K8 + kc + ch];
    }
    __syncthreads();
#pragma unroll
    for (int kk = 0; kk < 2; ++kk) {
      short8 af[4], bf[4];
#pragma unroll
      for (int m = 0; m < 4; ++m) {
        int row = wm + m * 16 + lr;
        af[m] = pA[row * 8 + ((kk * 4 + lg) ^ (row & 7))];
      }
#pragma unroll
      for (int n = 0; n < 4; ++n) {
        int row = wn + n * 16 + lr;
        bf[n] = pB[row * 8 + ((kk * 4 + lg) ^ (row & 7))];
      }
#pragma unroll
      for (int m = 0; m < 4; ++m)
#pragma unroll
        for (int n = 0; n < 4; ++n)
          acc[m][n] = __builtin_amdgcn_mfma_f32_16x16x32_bf16(af[m], bf[n], acc[m][n], 0, 0, 0);
    }
  }
#pragma unroll
  for (int m = 0; m < 4; ++m)
#pragma unroll
    for (int n = 0; n < 4; ++n)
#pragma unroll
      for (int j = 0; j < 4; ++j) {
        int r = m0 + wm + m * 16 + lg * 4 + j;
        int cc = n0 + wn + n * 16 + lr;
        C[(size_t)r * N + cc] = acc[m][n][j];
      }
}

// ---------------- QKV post-process ----------------
__global__ void qkv_post_txt(const float* __restrict__ QKV,
                             unsigned short* __restrict__ q_txt,
                             unsigned short* __restrict__ k_cat,
                             unsigned short* __restrict__ v_cat) {
  int blk = blockIdx.x;  // h*512 + s
  int h = blk >> 9, s = blk & 511;
  int d = threadIdx.x;  // 128
  const float* row = QKV + (size_t)s * 6144 + h * 128 + d;
  float q = row[0], k = row[2048], v = row[4096];
  q_txt[((size_t)h * 512 + s) * 128 + d] = f2bu(q);
  k_cat[((size_t)h * 2560 + s) * 128 + d] = f2bu(k);
  v_cat[((size_t)h * 2560 + s) * 128 + d] = f2bu(v);
}

__global__ void qkv_post_img(const float* __restrict__ QKV,
                             const float* __restrict__ rope,
                             const float* __restrict__ modb,
                             unsigned short* __restrict__ q_img,
                             unsigned short* __restrict__ k_cat,
                             unsigned short* __restrict__ v_cat) {
  int blk = blockIdx.x;  // h*2048 + s
  int h = blk >> 11, s = blk & 2047;
  int d = threadIdx.x;
  const float* row = QKV + (size_t)s * 6144 + h * 128 + d;
  float q = row[0], k = row[2048], v = row[4096];
  float c = rope[(size_t)s * 128 + (d & ~1)];
  float sn = rope[(size_t)s * 128 + (d | 1)];
  float qp = __shfl_xor(q, 1), kp = __shfl_xor(k, 1);
  float qr = (d & 1) ? (q * c + qp * sn) : (q * c - qp * sn);
  float kr = (d & 1) ? (k * c + kp * sn) : (k * c - kp * sn);
  float m = modb[h * 2048 + s];
  qr *= m; kr *= m;
  q_img[((size_t)h * 2048 + s) * 128 + d] = f2bu(qr);
  k_cat[((size_t)h * 2560 + 512 + s) * 128 + d] = f2bu(kr);
  v_cat[((size_t)h * 2560 + 512 + s) * 128 + d] = f2bu(v);
}

// ---------------- fused flash attention ----------------
__global__ __launch_bounds__(256) void attn_kernel(
    const unsigned short* __restrict__ Q, const unsigned short* __restrict__ Kc,
    const unsigned short* __restrict__ Vt, unsigned short* __restrict__ O,
    const float* __restrict__ scale_ptr, int qlen) {
  __shared__ int4 sQ[128 * 16];
  __shared__ int4 sK[64 * 16];  // reused as P (128x64 bf16) after QK phase
  __shared__ int4 sV[128 * 8];
  const int tid = threadIdx.x, w = tid >> 6, l = tid & 63, lr = l & 15, lg = l >> 4;
  const int h = blockIdx.y, q0 = blockIdx.x * 128;
  const float scale = *scale_ptr;
  const int4* Qg = reinterpret_cast<const int4*>(Q + ((size_t)h * qlen + q0) * 128);
#pragma unroll
  for (int i = 0; i < 8; ++i) {
    int c = i * 256 + tid, row = c >> 4, ch = c & 15;
    sQ[row * 16 + (ch ^ (row & 7))] = Qg[c];
  }
  f32x4 oacc[2][8] = {};
  float m_run[2][4], l_run[2][4];
#pragma unroll
  for (int m = 0; m < 2; ++m)
#pragma unroll
    for (int j = 0; j < 4; ++j) { m_run[m][j] = -1e30f; l_run[m][j] = 0.f; }
  const int4* Kg = reinterpret_cast<const int4*>(Kc + (size_t)h * 2560 * 128);
  const int4* Vg = reinterpret_cast<const int4*>(Vt + (size_t)h * 128 * 2560);
  const short8* pQ = reinterpret_cast<const short8*>(sQ);
  const short8* pK = reinterpret_cast<const short8*>(sK);
  const short8* pV = reinterpret_cast<const short8*>(sV);
  const short8* pP = reinterpret_cast<const short8*>(sK);
  unsigned short* sPb = reinterpret_cast<unsigned short*>(sK);

  for (int kt = 0; kt < 40; ++kt) {
    __syncthreads();
#pragma unroll
    for (int i = 0; i < 4; ++i) {
      int c = i * 256 + tid, row = c >> 4, ch = c & 15;
      sK[row * 16 + (ch ^ (row & 7))] = Kg[(size_t)kt * 1024 + c];
    }
#pragma unroll
    for (int i = 0; i < 4; ++i) {
      int c = i * 256 + tid, row = c >> 3, ch = c & 7;
      sV[row * 8 + (ch ^ (row & 7))] = Vg[(size_t)row * 320 + kt * 8 + ch];
    }
    __syncthreads();
    f32x4 sacc[2][4] = {};
#pragma unroll
    for (int ds = 0; ds < 4; ++ds) {
      short8 aq[2], bk[4];
#pragma unroll
      for (int m = 0; m < 2; ++m) {
        int row = w * 32 + m * 16 + lr;
        aq[m] = pQ[row * 16 + ((ds * 4 + lg) ^ (row & 7))];
      }
#pragma unroll
      for (int n = 0; n < 4; ++n) {
        int row = n * 16 + lr;
        bk[n] = pK[row * 16 + ((ds * 4 + lg) ^ (row & 7))];
      }
#pragma unroll
      for (int m = 0; m < 2; ++m)
#pragma unroll
        for (int n = 0; n < 4; ++n)
          sacc[m][n] = __builtin_amdgcn_mfma_f32_16x16x32_bf16(aq[m], bk[n], sacc[m][n], 0, 0, 0);
    }
    __syncthreads();  // all waves done reading sK before P overwrite
    float corr_[2][4];
#pragma unroll
    for (int m = 0; m < 2; ++m)
#pragma unroll
      for (int j = 0; j < 4; ++j) {
        float mx = -1e30f;
#pragma unroll
        for (int n = 0; n < 4; ++n) {
          sacc[m][n][j] *= scale;
          mx = fmaxf(mx, sacc[m][n][j]);
        }
        mx = fmaxf(mx, __shfl_xor(mx, 1));
        mx = fmaxf(mx, __shfl_xor(mx, 2));
        mx = fmaxf(mx, __shfl_xor(mx, 4));
        mx = fmaxf(mx, __shfl_xor(mx, 8));
        float mn = fmaxf(m_run[m][j], mx);
        float corr = __expf(m_run[m][j] - mn);
        m_run[m][j] = mn;
        float rs = 0.f;
#pragma unroll
        for (int n = 0; n < 4; ++n) {
          float p = __expf(sacc[m][n][j] - mn);
          sacc[m][n][j] = p;
          rs += p;
        }
        rs += __shfl_xor(rs, 1);
        rs += __shfl_xor(rs, 2);
        rs += __shfl_xor(rs, 4);
        rs += __shfl_xor(rs, 8);
        l_run[m][j] = l_run[m][j] * corr + rs;
        corr_[m][j] = corr;
      }
#pragma unroll
    for (int m = 0; m < 2; ++m)
#pragma unroll
      for (int n = 0; n < 8; ++n)
#pragma unroll
        for (int j = 0; j < 4; ++j) oacc[m][n][j] *= corr_[m][j];
    // write P (each wave owns its 32 q-rows)
#pragma unroll
    for (int m = 0; m < 2; ++m)
#pragma unroll
      for (int n = 0; n < 4; ++n)
#pragma unroll
        for (int j = 0; j < 4; ++j) {
          int row = w * 32 + m * 16 + lg * 4 + j;
          int col = n * 16 + lr;
          sPb[row * 64 + (((col >> 3) ^ (row & 7)) << 3) + (col & 7)] = f2bu(sacc[m][n][j]);
        }
    // PV
#pragma unroll
    for (int kk = 0; kk < 2; ++kk) {
      short8 ap[2], bv[8];
#pragma unroll
      for (int m = 0; m < 2; ++m) {
        int row = w * 32 + m * 16 + lr;
        ap[m] = pP[row * 8 + ((kk * 4 + lg) ^ (row & 7))];
      }
#pragma unroll
      for (int n = 0; n < 8; ++n) {
        int row = n * 16 + lr;
        bv[n] = pV[row * 8 + ((kk * 4 + lg) ^ (row & 7))];
      }
#pragma unroll
      for (int m = 0; m < 2; ++m)
#pragma unroll
        for (int n = 0; n < 8; ++n)
          oacc[m][n] = __builtin_amdgcn_mfma_f32_16x16x32_bf16(ap[m], bv[n], oacc[m][n], 0, 0, 0);
    }
  }
#pragma unroll
  for (int m = 0; m < 2; ++m)
#pragma unroll
    for (int j = 0; j < 4; ++j) {
      float inv = 1.f / l_run[m][j];
      int row = q0 + w * 32 + m * 16 + lg * 4 + j;
#pragma unroll
      for (int n = 0; n < 8; ++n)
        O[(size_t)row * 2048 + h * 128 + n * 16 + lr] = f2bu(oacc[m][n][j] * inv);
    }
}

// ---------------- residuals / gelu ----------------
__global__ __launch_bounds__(256) void residual1(
    const float4* __restrict__ X, const float4* __restrict__ P,
    const float* __restrict__ e, float4* __restrict__ out, int total4) {
  int stride = gridDim.x * 256;
  for (int i = blockIdx.x * 256 + threadIdx.x; i < total4; i += stride) {
    int c = (i * 4) & 2047;
    float4 g = *reinterpret_cast<const float4*>(e + 4096 + c);
    float4 x = X[i], p = P[i], o;
    o.x = x.x + g.x * p.x; o.y = x.y + g.y * p.y;
    o.z = x.z + g.z * p.z; o.w = x.w + g.w * p.w;
    out[i] = o;
  }
}

__global__ __launch_bounds__(256) void residual2(
    const float4* __restrict__ C2, const float* __restrict__ b2,
    const float* __restrict__ e, float4* __restrict__ out, int total4) {
  int stride = gridDim.x * 256;
  for (int i = blockIdx.x * 256 + threadIdx.x; i < total4; i += stride) {
    int c = (i * 4) & 2047;
    float4 g = *reinterpret_cast<const float4*>(e + 10240 + c);
    float4 bb = *reinterpret_cast<const float4*>(b2 + c);
    float4 v = C2[i], o = out[i];
    o.x += g.x * (v.x + bb.x); o.y += g.y * (v.y + bb.y);
    o.z += g.z * (v.z + bb.z); o.w += g.w * (v.w + bb.w);
    out[i] = o;
  }
}

__global__ __launch_bounds__(256) void gelu_bias(
    const float4* __restrict__ C, const float* __restrict__ bias,
    ushort4* __restrict__ out, int total4) {
  int stride = gridDim.x * 256;
  for (int i = blockIdx.x * 256 + threadIdx.x; i < total4; i += stride) {
    int c = (i * 4) & 8191;
    float4 bb = *reinterpret_cast<const float4*>(bias + c);
    float4 x = C[i];
    ushort4 o;
    o.x = f2bu(gelu_t(x.x + bb.x));
    o.y = f2bu(gelu_t(x.y + bb.y));
    o.z = f2bu(gelu_t(x.z + bb.z));
    o.w = f2bu(gelu_t(x.w + bb.w));
    out[i] = o;
  }
}

extern "C" void kernel_launch(void* const* d_in, const int* in_sizes, int n_in,
                              void* d_out, int out_size, void* d_ws, size_t ws_size,
                              hipStream_t stream) {
  (void)in_sizes; (void)n_in; (void)out_size; (void)ws_size;
  const float* txt = (const float*)d_in[0];
  const float* img = (const float*)d_in[1];
  const float* vec = (const float*)d_in[2];
  const float* rope = (const float*)d_in[3];
  const float* sol_t = (const float*)d_in[4];
  const float* sol_s = (const float*)d_in[5];
  const float* ada_img_w = (const float*)d_in[6];
  const float* ada_img_b = (const float*)d_in[7];
  const float* ada_img_nw = (const float*)d_in[8];
  const float* ada_txt_w = (const float*)d_in[9];
  const float* ada_txt_b = (const float*)d_in[10];
  const float* ada_txt_nw = (const float*)d_in[11];
  const float* txt_qkv_w = (const float*)d_in[12];
  const float* img_qkv_w = (const float*)d_in[13];
  const float* txt_out_w = (const float*)d_in[14];
  const float* img_out_w = (const float*)d_in[15];
  const float* mod_w = (const float*)d_in[16];
  const float* mod_b = (const float*)d_in[17];
  const float* img_n2_w = (const float*)d_in[18];
  const float* txt_n2_w = (const float*)d_in[19];
  const float* img_fc1_w = (const float*)d_in[20];
  const float* img_fc1_b = (const float*)d_in[21];
  const float* img_fc2_w = (const float*)d_in[22];
  const float* img_fc2_b = (const float*)d_in[23];
  const float* txt_fc1_w = (const float*)d_in[24];
  const float* txt_fc1_b = (const float*)d_in[25];
  const float* txt_fc2_w = (const float*)d_in[26];
  const float* txt_fc2_b = (const float*)d_in[27];
  float* out = (float*)d_out;
  char* ws = (char*)d_ws;

  float* silu_vec = (float*)(ws + 0);
  float* scales = (float*)(ws + 8192);
  float* modb = (float*)(ws + 16384);           // 16*2048 f32
  float* e_img = (float*)(ws + 147456);         // 12288 f32
  float* e_txt = (float*)(ws + 196608);         // 12288 f32
  size_t off = (size_t)1 << 20;
  unsigned short* wt = (unsigned short*)(ws + off);     off += 33554432;  // 32MB
  unsigned short* actA = (unsigned short*)(ws + off);   off += 33554432;  // 32MB
  unsigned short* q_txt = (unsigned short*)(ws + off);  off += 2097152;
  unsigned short* q_img = (unsigned short*)(ws + off);  off += 8388608;
  unsigned short* k_cat = (unsigned short*)(ws + off);  off += 10485760;
  unsigned short* v_cat = (unsigned short*)(ws + off);  off += 10485760;
  unsigned short* vT = (unsigned short*)(ws + off);     off += 10485760;
  unsigned short* ao_txt = (unsigned short*)(ws + off); off += 2097152;
  unsigned short* ao_img = (unsigned short*)(ws + off); off += 8388608;
  float* Cbuf = (float*)(ws + off);  // 64MB
  float* Cimg = Cbuf + (size_t)512 * 6144;
  float* out_img = out + (size_t)512 * 2048;

  prep_small<<<1, 256, 0, stream>>>(vec, sol_t, silu_vec, scales);
  mod_kernel<<<128, 256, 0, stream>>>(sol_s, mod_w, mod_b, modb);
  ada_gemv<<<dim3(192, 2), 256, 0, stream>>>(silu_vec, ada_img_w, ada_img_b,
                                             ada_txt_w, ada_txt_b, e_img, e_txt);
  // txt qkv
  rmsmod_kernel<<<512, 256, 0, stream>>>(txt, ada_txt_nw, e_txt, 0, 2048, actA);
  transpose_w<<<dim3(192, 64), dim3(32, 8), 0, stream>>>(txt_qkv_w, wt, 2048, 6144);
  gemm_kernel<<<dim3(48, 4), 256, 0, stream>>>(actA, wt, Cbuf, 512, 6144, 2048);
  // img qkv
  rmsmod_kernel<<<2048, 256, 0, stream>>>(img, ada_img_nw, e_img, 0, 2048, actA);
  transpose_w<<<dim3(192, 64), dim3(32, 8), 0, stream>>>(img_qkv_w, wt, 2048, 6144);
  gemm_kernel<<<dim3(48, 16), 256, 0, stream>>>(actA, wt, Cimg, 2048, 6144, 2048);
  qkv_post_txt<<<8192, 128, 0, stream>>>(Cbuf, q_txt, k_cat, v_cat);
  qkv_post_img<<<32768, 128, 0, stream>>>(Cimg, rope, modb, q_img, k_cat, v_cat);
  transpose_v<<<dim3(80, 4, 16), dim3(32, 8), 0, stream>>>(v_cat, vT);
  attn_kernel<<<dim3(4, 16), 256, 0, stream>>>(q_txt, k_cat, vT, ao_txt, scales + 0, 512);
  attn_kernel<<<dim3(16, 16), 256, 0, stream>>>(q_img, k_cat, vT, ao_img, scales + 1, 2048);
  // out projections + gated residual (into d_out)
  transpose_w<<<dim3(64, 64), dim3(32, 8), 0, stream>>>(txt_out_w, wt, 2048, 2048);
  gemm_kernel<<<dim3(16, 4), 256, 0, stream>>>(ao_txt, wt, Cbuf, 512, 2048, 2048);
  residual1<<<512, 256, 0, stream>>>((const float4*)txt, (const float4*)Cbuf, e_txt,
                                     (float4*)out, 512 * 2048 / 4);
  transpose_w<<<dim3(64, 64), dim3(32, 8), 0, stream>>>(img_out_w, wt, 2048, 2048);
  gemm_kernel<<<dim3(16, 16), 256, 0, stream>>>(ao_img, wt, Cbuf, 2048, 2048, 2048);
  residual1<<<1024, 256, 0, stream>>>((const float4*)img, (const float4*)Cbuf, e_img,
                                      (float4*)out_img, 2048 * 2048 / 4);
  // txt MLP
  rmsmod_kernel<<<512, 256, 0, stream>>>(out, txt_n2_w, e_txt, 6144, 8192, actA);
  transpose_w<<<dim3(256, 64), dim3(32, 8), 0, stream>>>(txt_fc1_w, wt, 2048, 8192);
  gemm_kernel<<<dim3(64, 4), 256, 0, stream>>>(actA, wt, Cbuf, 512, 8192, 2048);
  gelu_bias<<<1024, 256, 0, stream>>>((const float4*)Cbuf, txt_fc1_b, (ushort4*)actA,
                                      512 * 8192 / 4);
  transpose_w<<<dim3(64, 256), dim3(32, 8), 0, stream>>>(txt_fc2_w, wt, 8192, 2048);
  gemm_kernel<<<dim3(16, 4), 256, 0, stream>>>(actA, wt, Cbuf, 512, 2048, 8192);
  residual2<<<512, 256, 0, stream>>>((const float4*)Cbuf, txt_fc2_b, e_txt,
                                     (float4*)out, 512 * 2048 / 4);
  // img MLP
  rmsmod_kernel<<<2048, 256, 0, stream>>>(out_img, img_n2_w, e_img, 6144, 8192, actA);
  transpose_w<<<dim3(256, 64), dim3(32, 8), 0, stream>>>(img_fc1_w, wt, 2048, 8192);
  gemm_kernel<<<dim3(64, 16), 256, 0, stream>>>(actA, wt, Cbuf, 2048, 8192, 2048);
  gelu_bias<<<2048, 256, 0, stream>>>((const float4*)Cbuf, img_fc1_b, (ushort4*)actA,
                                      2048 * 8192 / 4);
  transpose_w<<<dim3(64, 256), dim3(32, 8), 0, stream>>>(img_fc2_w, wt, 8192, 2048);
  gemm_kernel<<<dim3(16, 16), 256, 0, stream>>>(actA, wt, Cbuf, 2048, 2048, 8192);
  residual2<<<1024, 256, 0, stream>>>((const float4*)Cbuf, img_fc2_b, e_img,
                                      (float4*)out_img, 2048 * 2048 / 4);
}

// Round 2
// 1157.266 us; speedup vs baseline: 1.0021x; 1.0021x over previous
//
#include <hip/hip_runtime.h>

typedef short short8 __attribute__((ext_vector_type(8)));
typedef float f32x4 __attribute__((ext_vector_type(4)));

__device__ __forceinline__ unsigned short f2bu(float f) {
  unsigned u = __builtin_bit_cast(unsigned, f);
  u += 0x7fffu + ((u >> 16) & 1u);
  return (unsigned short)(u >> 16);
}

__device__ __forceinline__ float gelu_t(float x) {
  float x3 = x * x * x;
  float t = tanhf(0.7978845608028654f * (x + 0.044715f * x3));
  return 0.5f * x * (1.f + t);
}

// async global->LDS, 16B per lane; lds base must be wave-uniform
__device__ __forceinline__ void gload16(const void* g, void* l) {
  __builtin_amdgcn_global_load_lds(
      (const __attribute__((address_space(1))) void*)g,
      (__attribute__((address_space(3))) void*)l, 16, 0, 0);
}

// ---------------- small prep: silu(vec), temperature scales ----------------
__global__ __launch_bounds__(256) void prep_small(
    const float* __restrict__ vec, const float* __restrict__ sol_t,
    float* __restrict__ silu_vec, float* __restrict__ scales) {
  __shared__ float red[4];
  int t = threadIdx.x;
  float v = (t < 64) ? sol_t[t] : 0.f;
#pragma unroll
  for (int o = 32; o > 0; o >>= 1) v += __shfl_down(v, o);
  if ((t & 63) == 0) red[t >> 6] = v;
  __syncthreads();
  if (t == 0) {
    float m = (red[0] + red[1] + red[2] + red[3]) * (1.f / 64.f);
    m = fmaxf(m, 0.1f);
    const float sc = 0.08838834764831845f;  // 128^-0.5
    scales[0] = sc;
    scales[1] = sc / m;  // s_eff^2 folded into score scale
  }
  for (int k = t; k < 2048; k += 256) {
    float x = vec[k];
    silu_vec[k] = x / (1.f + expf(-x));
  }
}

// ---------------- bilinear-resized modulation map ----------------
__global__ __launch_bounds__(256) void mod_kernel(
    const float* __restrict__ S, const float* __restrict__ mw,
    const float* __restrict__ mb, float* __restrict__ modb) {
  int idx = blockIdx.x * 256 + threadIdx.x;  // 16*2048
  int h = idx >> 11, n = idx & 2047;
  int y = n >> 5, x = n & 31;
  float cy = (y + 0.5f) * 0.125f - 0.5f;
  float cx = (x + 0.5f) * 0.25f - 0.5f;
  int y0 = (int)floorf(cy); float fy = cy - (float)y0;
  int x0 = (int)floorf(cx); float fx = cx - (float)x0;
  int y0c = min(max(y0, 0), 7), y1c = min(max(y0 + 1, 0), 7);
  int x0c = min(max(x0, 0), 7), x1c = min(max(x0 + 1, 0), 7);
  float v = (1.f - fy) * ((1.f - fx) * S[y0c * 8 + x0c] + fx * S[y0c * 8 + x1c]) +
            fy * ((1.f - fx) * S[y1c * 8 + x0c] + fx * S[y1c * 8 + x1c]);
  float t = v * mw[h] + mb[h];
  t = fminf(fmaxf(t, -2.f), 2.f);
  modb[idx] = expf(t);
}

// ---------------- adaLN GEMV: e = silu(vec) @ W + b ----------------
__global__ __launch_bounds__(256) void ada_gemv(
    const float* __restrict__ sv,
    const float* __restrict__ Wi, const float* __restrict__ bi,
    const float* __restrict__ Wt, const float* __restrict__ bt,
    float* __restrict__ ei, float* __restrict__ et) {
  __shared__ float red[4][64];
  const float* W = blockIdx.y ? Wt : Wi;
  const float* bb = blockIdx.y ? bt : bi;
  float* e = blockIdx.y ? et : ei;
  int jl = threadIdx.x & 63, ks = threadIdx.x >> 6;
  int j = blockIdx.x * 64 + jl;
  float acc = 0.f;
  int k0 = ks * 512;
#pragma unroll 4
  for (int k = 0; k < 512; ++k) acc += sv[k0 + k] * W[(size_t)(k0 + k) * 12288 + j];
  red[ks][jl] = acc;
  __syncthreads();
  if (ks == 0) e[j] = red[0][jl] + red[1][jl] + red[2][jl] + red[3][jl] + bb[j];
}

// ---------------- RMSNorm + adaLN modulate -> bf16 ----------------
__global__ __launch_bounds__(256) void rmsmod_kernel(
    const float* __restrict__ X, const float* __restrict__ nw,
    const float* __restrict__ e, int sh_off, int sc_off,
    unsigned short* __restrict__ out) {
  __shared__ float red[4];
  int r = blockIdx.x, t = threadIdx.x;
  const float4* xr = reinterpret_cast<const float4*>(X + (size_t)r * 2048);
  float4 v0 = xr[t * 2], v1 = xr[t * 2 + 1];
  float ss = v0.x * v0.x + v0.y * v0.y + v0.z * v0.z + v0.w * v0.w +
             v1.x * v1.x + v1.y * v1.y + v1.z * v1.z + v1.w * v1.w;
#pragma unroll
  for (int o = 32; o > 0; o >>= 1) ss += __shfl_down(ss, o);
  if ((t & 63) == 0) red[t >> 6] = ss;
  __syncthreads();
  float rinv = rsqrtf((red[0] + red[1] + red[2] + red[3]) * (1.f / 2048.f) + 1e-6f);
  int c0 = t * 8;
  float xv[8] = {v0.x, v0.y, v0.z, v0.w, v1.x, v1.y, v1.z, v1.w};
  short8 ov;
#pragma unroll
  for (int i = 0; i < 8; ++i) {
    int c = c0 + i;
    float y = xv[i] * rinv * nw[c] * (1.f + e[sc_off + c]) + e[sh_off + c];
    ov[i] = (short)f2bu(y);
  }
  *reinterpret_cast<short8*>(out + (size_t)r * 2048 + c0) = ov;
}

// ---------------- weight transpose+convert: f32 [K][N] -> bf16 [N][K] ----------------
__global__ __launch_bounds__(256) void transpose_w(
    const float* __restrict__ W, unsigned short* __restrict__ Bt, int K, int N) {
  __shared__ float tile[32][33];
  int n0 = blockIdx.x * 32, k0 = blockIdx.y * 32;
  int tx = threadIdx.x, ty = threadIdx.y;
#pragma unroll
  for (int j = 0; j < 32; j += 8)
    tile[ty + j][tx] = W[(size_t)(k0 + ty + j) * N + n0 + tx];
  __syncthreads();
#pragma unroll
  for (int j = 0; j < 32; j += 8)
    Bt[(size_t)(n0 + ty + j) * K + k0 + tx] = f2bu(tile[tx][ty + j]);
}

// ---------------- bf16 transpose for V: [16][2560][128] -> [16][128][2560] ----------------
__global__ __launch_bounds__(256) void transpose_v(
    const unsigned short* __restrict__ V, unsigned short* __restrict__ Vt) {
  __shared__ unsigned short tile[32][33];
  int h = blockIdx.z;
  int s0 = blockIdx.x * 32, d0 = blockIdx.y * 32;
  int tx = threadIdx.x, ty = threadIdx.y;
  const unsigned short* src = V + (size_t)h * 2560 * 128;
  unsigned short* dst = Vt + (size_t)h * 128 * 2560;
#pragma unroll
  for (int j = 0; j < 32; j += 8)
    tile[ty + j][tx] = src[(size_t)(s0 + ty + j) * 128 + d0 + tx];
  __syncthreads();
#pragma unroll
  for (int j = 0; j < 32; j += 8)
    dst[(size_t)(d0 + ty + j) * 2560 + s0 + tx] = tile[tx][ty + j];
}

// ---------------- GEMM: C[M][N] = A(bf16 [M][K]) * Bt(bf16 [N][K])^T ----------------
// EPI 0: f32 store to C.  EPI 1: bf16 gelu(acc+bias) store to Cb.
template <int EPI>
__global__ __launch_bounds__(256) void gemm_kernel(
    const unsigned short* __restrict__ A, const unsigned short* __restrict__ Bt,
    float* __restrict__ C, unsigned short* __restrict__ Cb,
    const float* __restrict__ bias, int M, int N, int K) {
  __shared__ int4 sA[128 * 8];
  __shared__ int4 sB[128 * 8];
  const int tid = threadIdx.x;
  const int m0 = blockIdx.y * 128, n0 = blockIdx.x * 128;
  const int w = tid >> 6, l = tid & 63, lr = l & 15, lg = l >> 4;
  const int wm = (w >> 1) * 64, wn = (w & 1) * 64;
  f32x4 acc[4][4] = {};
  const int4* Ag = reinterpret_cast<const int4*>(A);
  const int4* Bg = reinterpret_cast<const int4*>(Bt);
  const int K8 = K >> 3;
  const short8* pA = reinterpret_cast<const short8*>(sA);
  const short8* pB = reinterpret_cast<const short8*>(sB);
  // staging geometry: slot s = i*256+tid -> LDS row = s>>3, chunk = s&7 (linear dest).
  // source chunk is XOR-swizzled (involution), reads apply the same XOR.
  int srow[4], sch[4];
#pragma unroll
  for (int i = 0; i < 4; ++i) {
    int s = i * 256 + tid;
    srow[i] = s >> 3;
    sch[i] = (s & 7) ^ (srow[i] & 7);
  }
  for (int k0 = 0; k0 < K; k0 += 64) {
    __syncthreads();
    int kc = k0 >> 3;
#pragma unroll
    for (int i = 0; i < 4; ++i) {
      gload16(&Ag[(size_t)(m0 + srow[i]) * K8 + kc + sch[i]], &sA[i * 256 + w * 64]);
      gload16(&Bg[(size_t)(n0 + srow[i]) * K8 + kc + sch[i]], &sB[i * 256 + w * 64]);
    }
    __syncthreads();
#pragma unroll
    for (int kk = 0; kk < 2; ++kk) {
      short8 af[4], bf[4];
#pragma unroll
      for (int m = 0; m < 4; ++m) {
        int row = wm + m * 16 + lr;
        af[m] = pA[row * 8 + ((kk * 4 + lg) ^ (row & 7))];
      }
#pragma unroll
      for (int n = 0; n < 4; ++n) {
        int row = wn + n * 16 + lr;
        bf[n] = pB[row * 8 + ((kk * 4 + lg) ^ (row & 7))];
      }
#pragma unroll
      for (int m = 0; m < 4; ++m)
#pragma unroll
        for (int n = 0; n < 4; ++n)
          acc[m][n] = __builtin_amdgcn_mfma_f32_16x16x32_bf16(af[m], bf[n], acc[m][n], 0, 0, 0);
    }
  }
  if (EPI == 0) {
#pragma unroll
    for (int m = 0; m < 4; ++m)
#pragma unroll
      for (int n = 0; n < 4; ++n)
#pragma unroll
        for (int j = 0; j < 4; ++j) {
          int r = m0 + wm + m * 16 + lg * 4 + j;
          int cc = n0 + wn + n * 16 + lr;
          C[(size_t)r * N + cc] = acc[m][n][j];
        }
  } else {
#pragma unroll
    for (int n = 0; n < 4; ++n) {
      int cc = n0 + wn + n * 16 + lr;
      float bv = bias[cc];
#pragma unroll
      for (int m = 0; m < 4; ++m)
#pragma unroll
        for (int j = 0; j < 4; ++j) {
          int r = m0 + wm + m * 16 + lg * 4 + j;
          Cb[(size_t)r * N + cc] = f2bu(gelu_t(acc[m][n][j] + bv));
        }
    }
  }
}

// ---------------- QKV post-process ----------------
__global__ void qkv_post_txt(const float* __restrict__ QKV,
                             unsigned short* __restrict__ q_txt,
                             unsigned short* __restrict__ k_cat,
                             unsigned short* __restrict__ v_cat) {
  int blk = blockIdx.x;  // h*512 + s
  int h = blk >> 9, s = blk & 511;
  int d = threadIdx.x;  // 128
  const float* row = QKV + (size_t)s * 6144 + h * 128 + d;
  float q = row[0], k = row[2048], v = row[4096];
  q_txt[((size_t)h * 512 + s) * 128 + d] = f2bu(q);
  k_cat[((size_t)h * 2560 + s) * 128 + d] = f2bu(k);
  v_cat[((size_t)h * 2560 + s) * 128 + d] = f2bu(v);
}

__global__ void qkv_post_img(const float* __restrict__ QKV,
                             const float* __restrict__ rope,
                             const float* __restrict__ modb,
                             unsigned short* __restrict__ q_img,
                             unsigned short* __restrict__ k_cat,
                             unsigned short* __restrict__ v_cat) {
  int blk = blockIdx.x;  // h*2048 + s
  int h = blk >> 11, s = blk & 2047;
  int d = threadIdx.x;
  const float* row = QKV + (size_t)s * 6144 + h * 128 + d;
  float q = row[0], k = row[2048], v = row[4096];
  float c = rope[(size_t)s * 128 + (d & ~1)];
  float sn = rope[(size_t)s * 128 + (d | 1)];
  float qp = __shfl_xor(q, 1), kp = __shfl_xor(k, 1);
  float qr = (d & 1) ? (q * c + qp * sn) : (q * c - qp * sn);
  float kr = (d & 1) ? (k * c + kp * sn) : (k * c - kp * sn);
  float m = modb[h * 2048 + s];
  qr *= m; kr *= m;
  q_img[((size_t)h * 2048 + s) * 128 + d] = f2bu(qr);
  k_cat[((size_t)h * 2560 + 512 + s) * 128 + d] = f2bu(kr);
  v_cat[((size_t)h * 2560 + 512 + s) * 128 + d] = f2bu(v);
}

// ---------------- fused flash attention ----------------
__global__ __launch_bounds__(256) void attn_kernel(
    const unsigned short* __restrict__ Q, const unsigned short* __restrict__ Kc,
    const unsigned short* __restrict__ Vt, unsigned short* __restrict__ O,
    const float* __restrict__ scale_ptr, int qlen) {
  __shared__ int4 sQ[128 * 16];
  __shared__ int4 sK[64 * 16];  // reused as P (128x64 bf16) after QK phase
  __shared__ int4 sV[128 * 8];
  const int tid = threadIdx.x, w = tid >> 6, l = tid & 63, lr = l & 15, lg = l >> 4;
  const int h = blockIdx.y, q0 = blockIdx.x * 128;
  const float scale = *scale_ptr;
  const int4* Qg = reinterpret_cast<const int4*>(Q + ((size_t)h * qlen + q0) * 128);
#pragma unroll
  for (int i = 0; i < 8; ++i) {
    int c = i * 256 + tid, row = c >> 4, ch = c & 15;
    sQ[row * 16 + (ch ^ (row & 7))] = Qg[c];
  }
  f32x4 oacc[2][8] = {};
  float m_run[2][4], l_run[2][4];
#pragma unroll
  for (int m = 0; m < 2; ++m)
#pragma unroll
    for (int j = 0; j < 4; ++j) { m_run[m][j] = -1e30f; l_run[m][j] = 0.f; }
  const int4* Kg = reinterpret_cast<const int4*>(Kc + (size_t)h * 2560 * 128);
  const int4* Vg = reinterpret_cast<const int4*>(Vt + (size_t)h * 128 * 2560);
  const short8* pQ = reinterpret_cast<const short8*>(sQ);
  const short8* pK = reinterpret_cast<const short8*>(sK);
  const short8* pV = reinterpret_cast<const short8*>(sV);
  const short8* pP = reinterpret_cast<const short8*>(sK);
  unsigned short* sPb = reinterpret_cast<unsigned short*>(sK);

  for (int kt = 0; kt < 40; ++kt) {
    __syncthreads();
#pragma unroll
    for (int i = 0; i < 4; ++i) {
      int c = i * 256 + tid, row = c >> 4, ch = c & 15;
      sK[row * 16 + (ch ^ (row & 7))] = Kg[(size_t)kt * 1024 + c];
    }
#pragma unroll
    for (int i = 0; i < 4; ++i) {
      int c = i * 256 + tid, row = c >> 3, ch = c & 7;
      sV[row * 8 + (ch ^ (row & 7))] = Vg[(size_t)row * 320 + kt * 8 + ch];
    }
    __syncthreads();
    f32x4 sacc[2][4] = {};
#pragma unroll
    for (int ds = 0; ds < 4; ++ds) {
      short8 aq[2], bk[4];
#pragma unroll
      for (int m = 0; m < 2; ++m) {
        int row = w * 32 + m * 16 + lr;
        aq[m] = pQ[row * 16 + ((ds * 4 + lg) ^ (row & 7))];
      }
#pragma unroll
      for (int n = 0; n < 4; ++n) {
        int row = n * 16 + lr;
        bk[n] = pK[row * 16 + ((ds * 4 + lg) ^ (row & 7))];
      }
#pragma unroll
      for (int m = 0; m < 2; ++m)
#pragma unroll
        for (int n = 0; n < 4; ++n)
          sacc[m][n] = __builtin_amdgcn_mfma_f32_16x16x32_bf16(aq[m], bk[n], sacc[m][n], 0, 0, 0);
    }
    __syncthreads();  // all waves done reading sK before P overwrite
    float corr_[2][4];
#pragma unroll
    for (int m = 0; m < 2; ++m)
#pragma unroll
      for (int j = 0; j < 4; ++j) {
        float mx = -1e30f;
#pragma unroll
        for (int n = 0; n < 4; ++n) {
          sacc[m][n][j] *= scale;
          mx = fmaxf(mx, sacc[m][n][j]);
        }
        mx = fmaxf(mx, __shfl_xor(mx, 1));
        mx = fmaxf(mx, __shfl_xor(mx, 2));
        mx = fmaxf(mx, __shfl_xor(mx, 4));
        mx = fmaxf(mx, __shfl_xor(mx, 8));
        float mn = fmaxf(m_run[m][j], mx);
        float corr = __expf(m_run[m][j] - mn);
        m_run[m][j] = mn;
        float rs = 0.f;
#pragma unroll
        for (int n = 0; n < 4; ++n) {
          float p = __expf(sacc[m][n][j] - mn);
          sacc[m][n][j] = p;
          rs += p;
        }
        rs += __shfl_xor(rs, 1);
        rs += __shfl_xor(rs, 2);
        rs += __shfl_xor(rs, 4);
        rs += __shfl_xor(rs, 8);
        l_run[m][j] = l_run[m][j] * corr + rs;
        corr_[m][j] = corr;
      }
#pragma unroll
    for (int m = 0; m < 2; ++m)
#pragma unroll
      for (int n = 0; n < 8; ++n)
#pragma unroll
        for (int j = 0; j < 4; ++j) oacc[m][n][j] *= corr_[m][j];
    // write P (each wave owns its 32 q-rows)
#pragma unroll
    for (int m = 0; m < 2; ++m)
#pragma unroll
      for (int n = 0; n < 4; ++n)
#pragma unroll
        for (int j = 0; j < 4; ++j) {
          int row = w * 32 + m * 16 + lg * 4 + j;
          int col = n * 16 + lr;
          sPb[row * 64 + (((col >> 3) ^ (row & 7)) << 3) + (col & 7)] = f2bu(sacc[m][n][j]);
        }
    // PV
#pragma unroll
    for (int kk = 0; kk < 2; ++kk) {
      short8 ap[2], bv[8];
#pragma unroll
      for (int m = 0; m < 2; ++m) {
        int row = w * 32 + m * 16 + lr;
        ap[m] = pP[row * 8 + ((kk * 4 + lg) ^ (row & 7))];
      }
#pragma unroll
      for (int n = 0; n < 8; ++n) {
        int row = n * 16 + lr;
        bv[n] = pV[row * 8 + ((kk * 4 + lg) ^ (row & 7))];
      }
#pragma unroll
      for (int m = 0; m < 2; ++m)
#pragma unroll
        for (int n = 0; n < 8; ++n)
          oacc[m][n] = __builtin_amdgcn_mfma_f32_16x16x32_bf16(ap[m], bv[n], oacc[m][n], 0, 0, 0);
    }
  }
#pragma unroll
  for (int m = 0; m < 2; ++m)
#pragma unroll
    for (int j = 0; j < 4; ++j) {
      float inv = 1.f / l_run[m][j];
      int row = q0 + w * 32 + m * 16 + lg * 4 + j;
#pragma unroll
      for (int n = 0; n < 8; ++n)
        O[(size_t)row * 2048 + h * 128 + n * 16 + lr] = f2bu(oacc[m][n][j] * inv);
    }
}

// ---------------- residuals ----------------
__global__ __launch_bounds__(256) void residual1(
    const float4* __restrict__ X, const float4* __restrict__ P,
    const float* __restrict__ e, float4* __restrict__ out, int total4) {
  int stride = gridDim.x * 256;
  for (int i = blockIdx.x * 256 + threadIdx.x; i < total4; i += stride) {
    int c = (i * 4) & 2047;
    float4 g = *reinterpret_cast<const float4*>(e + 4096 + c);
    float4 x = X[i], p = P[i], o;
    o.x = x.x + g.x * p.x; o.y = x.y + g.y * p.y;
    o.z = x.z + g.z * p.z; o.w = x.w + g.w * p.w;
    out[i] = o;
  }
}

__global__ __launch_bounds__(256) void residual2(
    const float4* __restrict__ C2, const float* __restrict__ b2,
    const float* __restrict__ e, float4* __restrict__ out, int total4) {
  int stride = gridDim.x * 256;
  for (int i = blockIdx.x * 256 + threadIdx.x; i < total4; i += stride) {
    int c = (i * 4) & 2047;
    float4 g = *reinterpret_cast<const float4*>(e + 10240 + c);
    float4 bb = *reinterpret_cast<const float4*>(b2 + c);
    float4 v = C2[i], o = out[i];
    o.x += g.x * (v.x + bb.x); o.y += g.y * (v.y + bb.y);
    o.z += g.z * (v.z + bb.z); o.w += g.w * (v.w + bb.w);
    out[i] = o;
  }
}

extern "C" void kernel_launch(void* const* d_in, const int* in_sizes, int n_in,
                              void* d_out, int out_size, void* d_ws, size_t ws_size,
                              hipStream_t stream) {
  (void)in_sizes; (void)n_in; (void)out_size; (void)ws_size;
  const float* txt = (const float*)d_in[0];
  const float* img = (const float*)d_in[1];
  const float* vec = (const float*)d_in[2];
  const float* rope = (const float*)d_in[3];
  const float* sol_t = (const float*)d_in[4];
  const float* sol_s = (const float*)d_in[5];
  const float* ada_img_w = (const float*)d_in[6];
  const float* ada_img_b = (const float*)d_in[7];
  const float* ada_img_nw = (const float*)d_in[8];
  const float* ada_txt_w = (const float*)d_in[9];
  const float* ada_txt_b = (const float*)d_in[10];
  const float* ada_txt_nw = (const float*)d_in[11];
  const float* txt_qkv_w = (const float*)d_in[12];
  const float* img_qkv_w = (const float*)d_in[13];
  const float* txt_out_w = (const float*)d_in[14];
  const float* img_out_w = (const float*)d_in[15];
  const float* mod_w = (const float*)d_in[16];
  const float* mod_b = (const float*)d_in[17];
  const float* img_n2_w = (const float*)d_in[18];
  const float* txt_n2_w = (const float*)d_in[19];
  const float* img_fc1_w = (const float*)d_in[20];
  const float* img_fc1_b = (const float*)d_in[21];
  const float* img_fc2_w = (const float*)d_in[22];
  const float* img_fc2_b = (const float*)d_in[23];
  const float* txt_fc1_w = (const float*)d_in[24];
  const float* txt_fc1_b = (const float*)d_in[25];
  const float* txt_fc2_w = (const float*)d_in[26];
  const float* txt_fc2_b = (const float*)d_in[27];
  float* out = (float*)d_out;
  char* ws = (char*)d_ws;

  float* silu_vec = (float*)(ws + 0);
  float* scales = (float*)(ws + 8192);
  float* modb = (float*)(ws + 16384);           // 16*2048 f32
  float* e_img = (float*)(ws + 147456);         // 12288 f32
  float* e_txt = (float*)(ws + 196608);         // 12288 f32
  size_t off = (size_t)1 << 20;
  unsigned short* wt = (unsigned short*)(ws + off);     off += 33554432;  // 32MB
  unsigned short* actA = (unsigned short*)(ws + off);   off += 33554432;  // 32MB
  char* attn_base = ws + off;
  unsigned short* q_txt = (unsigned short*)(ws + off);  off += 2097152;
  unsigned short* q_img = (unsigned short*)(ws + off);  off += 8388608;
  unsigned short* k_cat = (unsigned short*)(ws + off);  off += 10485760;
  unsigned short* v_cat = (unsigned short*)(ws + off);  off += 10485760;
  unsigned short* vT = (unsigned short*)(ws + off);     off += 10485760;
  unsigned short* ao_txt = (unsigned short*)(ws + off); off += 2097152;
  unsigned short* ao_img = (unsigned short*)(ws + off); off += 8388608;
  float* Cbuf = (float*)(ws + off);  // 64MB
  float* Cimg = Cbuf + (size_t)512 * 6144;
  float* out_img = out + (size_t)512 * 2048;
  // fc1 bf16 outputs reuse the (dead by MLP-phase) attention buffer region (50MB >= 32MB)
  unsigned short* actB = (unsigned short*)attn_base;

  prep_small<<<1, 256, 0, stream>>>(vec, sol_t, silu_vec, scales);
  mod_kernel<<<128, 256, 0, stream>>>(sol_s, mod_w, mod_b, modb);
  ada_gemv<<<dim3(192, 2), 256, 0, stream>>>(silu_vec, ada_img_w, ada_img_b,
                                             ada_txt_w, ada_txt_b, e_img, e_txt);
  // txt qkv
  rmsmod_kernel<<<512, 256, 0, stream>>>(txt, ada_txt_nw, e_txt, 0, 2048, actA);
  transpose_w<<<dim3(192, 64), dim3(32, 8), 0, stream>>>(txt_qkv_w, wt, 2048, 6144);
  gemm_kernel<0><<<dim3(48, 4), 256, 0, stream>>>(actA, wt, Cbuf, nullptr, nullptr, 512, 6144, 2048);
  // img qkv
  rmsmod_kernel<<<2048, 256, 0, stream>>>(img, ada_img_nw, e_img, 0, 2048, actA);
  transpose_w<<<dim3(192, 64), dim3(32, 8), 0, stream>>>(img_qkv_w, wt, 2048, 6144);
  gemm_kernel<0><<<dim3(48, 16), 256, 0, stream>>>(actA, wt, Cimg, nullptr, nullptr, 2048, 6144, 2048);
  qkv_post_txt<<<8192, 128, 0, stream>>>(Cbuf, q_txt, k_cat, v_cat);
  qkv_post_img<<<32768, 128, 0, stream>>>(Cimg, rope, modb, q_img, k_cat, v_cat);
  transpose_v<<<dim3(80, 4, 16), dim3(32, 8), 0, stream>>>(v_cat, vT);
  attn_kernel<<<dim3(4, 16), 256, 0, stream>>>(q_txt, k_cat, vT, ao_txt, scales + 0, 512);
  attn_kernel<<<dim3(16, 16), 256, 0, stream>>>(q_img, k_cat, vT, ao_img, scales + 1, 2048);
  // out projections + gated residual (into d_out)
  transpose_w<<<dim3(64, 64), dim3(32, 8), 0, stream>>>(txt_out_w, wt, 2048, 2048);
  gemm_kernel<0><<<dim3(16, 4), 256, 0, stream>>>(ao_txt, wt, Cbuf, nullptr, nullptr, 512, 2048, 2048);
  residual1<<<512, 256, 0, stream>>>((const float4*)txt, (const float4*)Cbuf, e_txt,
                                     (float4*)out, 512 * 2048 / 4);
  transpose_w<<<dim3(64, 64), dim3(32, 8), 0, stream>>>(img_out_w, wt, 2048, 2048);
  gemm_kernel<0><<<dim3(16, 16), 256, 0, stream>>>(ao_img, wt, Cbuf, nullptr, nullptr, 2048, 2048, 2048);
  residual1<<<1024, 256, 0, stream>>>((const float4*)img, (const float4*)Cbuf, e_img,
                                      (float4*)out_img, 2048 * 2048 / 4);
  // txt MLP
  rmsmod_kernel<<<512, 256, 0, stream>>>(out, txt_n2_w, e_txt, 6144, 8192, actA);
  transpose_w<<<dim3(256, 64), dim3(32, 8), 0, stream>>>(txt_fc1_w, wt, 2048, 8192);
  gemm_kernel<1><<<dim3(64, 4), 256, 0, stream>>>(actA, wt, nullptr, actB, txt_fc1_b, 512, 8192, 2048);
  transpose_w<<<dim3(64, 256), dim3(32, 8), 0, stream>>>(txt_fc2_w, wt, 8192, 2048);
  gemm_kernel<0><<<dim3(16, 4), 256, 0, stream>>>(actB, wt, Cbuf, nullptr, nullptr, 512, 2048, 8192);
  residual2<<<512, 256, 0, stream>>>((const float4*)Cbuf, txt_fc2_b, e_txt,
                                     (float4*)out, 512 * 2048 / 4);
  // img MLP
  rmsmod_kernel<<<2048, 256, 0, stream>>>(out_img, img_n2_w, e_img, 6144, 8192, actA);
  transpose_w<<<dim3(256, 64), dim3(32, 8), 0, stream>>>(img_fc1_w, wt, 2048, 8192);
  gemm_kernel<1><<<dim3(64, 16), 256, 0, stream>>>(actA, wt, nullptr, actB, img_fc1_b, 2048, 8192, 2048);
  transpose_w<<<dim3(64, 256), dim3(32, 8), 0, stream>>>(img_fc2_w, wt, 8192, 2048);
  gemm_kernel<0><<<dim3(16, 16), 256, 0, stream>>>(actB, wt, Cbuf, nullptr, nullptr, 2048, 2048, 8192);
  residual2<<<1024, 256, 0, stream>>>((const float4*)Cbuf, img_fc2_b, e_img,
                                      (float4*)out_img, 2048 * 2048 / 4);
}

// Round 3
// 991.524 us; speedup vs baseline: 1.1696x; 1.1672x over previous
//
#include <hip/hip_runtime.h>

typedef short short8 __attribute__((ext_vector_type(8)));
typedef float f32x4 __attribute__((ext_vector_type(4)));

__device__ __forceinline__ unsigned short f2bu(float f) {
  unsigned u = __builtin_bit_cast(unsigned, f);
  u += 0x7fffu + ((u >> 16) & 1u);
  return (unsigned short)(u >> 16);
}

__device__ __forceinline__ float gelu_t(float x) {
  float x3 = x * x * x;
  float t = tanhf(0.7978845608028654f * (x + 0.044715f * x3));
  return 0.5f * x * (1.f + t);
}

__device__ __forceinline__ void gload16(const void* g, void* l) {
  __builtin_amdgcn_global_load_lds(
      (const __attribute__((address_space(1))) void*)g,
      (__attribute__((address_space(3))) void*)l, 16, 0, 0);
}

// ---------------- small prep ----------------
__global__ __launch_bounds__(256) void prep_small(
    const float* __restrict__ vec, const float* __restrict__ sol_t,
    float* __restrict__ silu_vec, float* __restrict__ scales) {
  __shared__ float red[4];
  int t = threadIdx.x;
  float v = (t < 64) ? sol_t[t] : 0.f;
#pragma unroll
  for (int o = 32; o > 0; o >>= 1) v += __shfl_down(v, o);
  if ((t & 63) == 0) red[t >> 6] = v;
  __syncthreads();
  if (t == 0) {
    float m = (red[0] + red[1] + red[2] + red[3]) * (1.f / 64.f);
    m = fmaxf(m, 0.1f);
    const float sc = 0.08838834764831845f;  // 128^-0.5
    scales[0] = sc;
    scales[1] = sc / m;  // s_eff^2 folded into score scale
  }
  for (int k = t; k < 2048; k += 256) {
    float x = vec[k];
    silu_vec[k] = x / (1.f + expf(-x));
  }
}

__global__ __launch_bounds__(256) void mod_kernel(
    const float* __restrict__ S, const float* __restrict__ mw,
    const float* __restrict__ mb, float* __restrict__ modb) {
  int idx = blockIdx.x * 256 + threadIdx.x;  // 16*2048
  int h = idx >> 11, n = idx & 2047;
  int y = n >> 5, x = n & 31;
  float cy = (y + 0.5f) * 0.125f - 0.5f;
  float cx = (x + 0.5f) * 0.25f - 0.5f;
  int y0 = (int)floorf(cy); float fy = cy - (float)y0;
  int x0 = (int)floorf(cx); float fx = cx - (float)x0;
  int y0c = min(max(y0, 0), 7), y1c = min(max(y0 + 1, 0), 7);
  int x0c = min(max(x0, 0), 7), x1c = min(max(x0 + 1, 0), 7);
  float v = (1.f - fy) * ((1.f - fx) * S[y0c * 8 + x0c] + fx * S[y0c * 8 + x1c]) +
            fy * ((1.f - fx) * S[y1c * 8 + x0c] + fx * S[y1c * 8 + x1c]);
  float t = v * mw[h] + mb[h];
  t = fminf(fmaxf(t, -2.f), 2.f);
  modb[idx] = expf(t);
}

__global__ __launch_bounds__(256) void ada_gemv(
    const float* __restrict__ sv,
    const float* __restrict__ Wi, const float* __restrict__ bi,
    const float* __restrict__ Wt, const float* __restrict__ bt,
    float* __restrict__ ei, float* __restrict__ et) {
  __shared__ float red[4][64];
  const float* W = blockIdx.y ? Wt : Wi;
  const float* bb = blockIdx.y ? bt : bi;
  float* e = blockIdx.y ? et : ei;
  int jl = threadIdx.x & 63, ks = threadIdx.x >> 6;
  int j = blockIdx.x * 64 + jl;
  float acc = 0.f;
  int k0 = ks * 512;
#pragma unroll 4
  for (int k = 0; k < 512; ++k) acc += sv[k0 + k] * W[(size_t)(k0 + k) * 12288 + j];
  red[ks][jl] = acc;
  __syncthreads();
  if (ks == 0) e[j] = red[0][jl] + red[1][jl] + red[2][jl] + red[3][jl] + bb[j];
}

// ---------------- RMSNorm + adaLN modulate -> bf16 ----------------
__global__ __launch_bounds__(256) void rmsmod_kernel(
    const float* __restrict__ X, const float* __restrict__ nw,
    const float* __restrict__ e, int sh_off, int sc_off,
    unsigned short* __restrict__ out) {
  __shared__ float red[4];
  int r = blockIdx.x, t = threadIdx.x;
  const float4* xr = reinterpret_cast<const float4*>(X + (size_t)r * 2048);
  float4 v0 = xr[t * 2], v1 = xr[t * 2 + 1];
  float ss = v0.x * v0.x + v0.y * v0.y + v0.z * v0.z + v0.w * v0.w +
             v1.x * v1.x + v1.y * v1.y + v1.z * v1.z + v1.w * v1.w;
#pragma unroll
  for (int o = 32; o > 0; o >>= 1) ss += __shfl_down(ss, o);
  if ((t & 63) == 0) red[t >> 6] = ss;
  __syncthreads();
  float rinv = rsqrtf((red[0] + red[1] + red[2] + red[3]) * (1.f / 2048.f) + 1e-6f);
  int c0 = t * 8;
  float xv[8] = {v0.x, v0.y, v0.z, v0.w, v1.x, v1.y, v1.z, v1.w};
  short8 ov;
#pragma unroll
  for (int i = 0; i < 8; ++i) {
    int c = c0 + i;
    float y = xv[i] * rinv * nw[c] * (1.f + e[sc_off + c]) + e[sh_off + c];
    ov[i] = (short)f2bu(y);
  }
  *reinterpret_cast<short8*>(out + (size_t)r * 2048 + c0) = ov;
}

// ---------------- weight transpose+convert ----------------
__global__ __launch_bounds__(256) void transpose_w(
    const float* __restrict__ W, unsigned short* __restrict__ Bt, int K, int N) {
  __shared__ float tile[32][33];
  int n0 = blockIdx.x * 32, k0 = blockIdx.y * 32;
  int tx = threadIdx.x, ty = threadIdx.y;
#pragma unroll
  for (int j = 0; j < 32; j += 8)
    tile[ty + j][tx] = W[(size_t)(k0 + ty + j) * N + n0 + tx];
  __syncthreads();
#pragma unroll
  for (int j = 0; j < 32; j += 8)
    Bt[(size_t)(n0 + ty + j) * K + k0 + tx] = f2bu(tile[tx][ty + j]);
}

__global__ __launch_bounds__(256) void transpose_v(
    const unsigned short* __restrict__ V, unsigned short* __restrict__ Vt) {
  __shared__ unsigned short tile[32][33];
  int h = blockIdx.z;
  int s0 = blockIdx.x * 32, d0 = blockIdx.y * 32;
  int tx = threadIdx.x, ty = threadIdx.y;
  const unsigned short* src = V + (size_t)h * 2560 * 128;
  unsigned short* dst = Vt + (size_t)h * 128 * 2560;
#pragma unroll
  for (int j = 0; j < 32; j += 8)
    tile[ty + j][tx] = src[(size_t)(s0 + ty + j) * 128 + d0 + tx];
  __syncthreads();
#pragma unroll
  for (int j = 0; j < 32; j += 8)
    dst[(size_t)(d0 + ty + j) * 2560 + s0 + tx] = tile[tx][ty + j];
}

// ---------------- batched GEMM (txt rows 0..511, img rows 512..2559) ----------------
// EPI 0: f32 partial store (split-K).  EPI 1: bf16 gelu(acc+bias).  EPI 2: qkv scatter.
struct GemmP {
  const unsigned short *A, *Bt_t, *Bt_i;
  float* C;            // f32 partial base; z-stride = Mtot*N
  unsigned short* Cb;  // bf16 merged out (EPI 1)
  const float *bias_t, *bias_i;
  const float *rope, *modb;
  unsigned short *q_txt, *q_img, *k_cat, *v_cat;
  int Mb_t;  // txt m-blocks (4)
  int N, K, KS;
};

template <int EPI>
__global__ __launch_bounds__(256) void gemm2(GemmP p) {
  __shared__ int4 sA[128 * 8];
  __shared__ int4 sB[128 * 8];
  const int NB = gridDim.x, MBT = gridDim.y;
  // bijective XCD swizzle (m204), column-major decode: same-n blocks share an XCD
  int nwg = NB * MBT;
  int orig = blockIdx.y * NB + blockIdx.x;
  int qq = nwg >> 3, rr = nwg & 7, xcd = orig & 7, base = orig >> 3;
  int sw = (xcd < rr ? xcd * (qq + 1) : rr * (qq + 1) + (xcd - rr) * qq) + base;
  int bx = sw / MBT, by = sw % MBT;
  const bool is_t = by < p.Mb_t;
  const unsigned short* Bt = is_t ? p.Bt_t : p.Bt_i;
  const int m0 = by * 128, n0 = bx * 128;
  const int z = blockIdx.z;
  const int Kz = p.K / p.KS, kbeg = z * Kz, kend = kbeg + Kz;
  const int tid = threadIdx.x;
  const int w = tid >> 6, l = tid & 63, lr = l & 15, lg = l >> 4;
  const int wm = (w >> 1) * 64, wn = (w & 1) * 64;
  f32x4 acc[4][4] = {};
  const int4* Ag = reinterpret_cast<const int4*>(p.A);
  const int4* Bg = reinterpret_cast<const int4*>(Bt);
  const int K8 = p.K >> 3;
  const short8* pA = reinterpret_cast<const short8*>(sA);
  const short8* pB = reinterpret_cast<const short8*>(sB);
  int srow[4], sch[4];
#pragma unroll
  for (int i = 0; i < 4; ++i) {
    int s = i * 256 + tid;
    srow[i] = s >> 3;
    sch[i] = (s & 7) ^ (srow[i] & 7);
  }
  for (int k0 = kbeg; k0 < kend; k0 += 64) {
    __syncthreads();
    int kc = k0 >> 3;
#pragma unroll
    for (int i = 0; i < 4; ++i) {
      gload16(&Ag[(size_t)(m0 + srow[i]) * K8 + kc + sch[i]], &sA[i * 256 + w * 64]);
      gload16(&Bg[(size_t)(n0 + srow[i]) * K8 + kc + sch[i]], &sB[i * 256 + w * 64]);
    }
    __syncthreads();
#pragma unroll
    for (int kk = 0; kk < 2; ++kk) {
      short8 af[4], bf[4];
#pragma unroll
      for (int m = 0; m < 4; ++m) {
        int row = wm + m * 16 + lr;
        af[m] = pA[row * 8 + ((kk * 4 + lg) ^ (row & 7))];
      }
#pragma unroll
      for (int n = 0; n < 4; ++n) {
        int row = wn + n * 16 + lr;
        bf[n] = pB[row * 8 + ((kk * 4 + lg) ^ (row & 7))];
      }
#pragma unroll
      for (int m = 0; m < 4; ++m)
#pragma unroll
        for (int n = 0; n < 4; ++n)
          acc[m][n] = __builtin_amdgcn_mfma_f32_16x16x32_bf16(af[m], bf[n], acc[m][n], 0, 0, 0);
    }
  }
  if (EPI == 0) {
    float* C = p.C + (size_t)z * MBT * 128 * p.N;
#pragma unroll
    for (int m = 0; m < 4; ++m)
#pragma unroll
      for (int n = 0; n < 4; ++n)
#pragma unroll
        for (int j = 0; j < 4; ++j) {
          int r = m0 + wm + m * 16 + lg * 4 + j;
          int cc = n0 + wn + n * 16 + lr;
          C[(size_t)r * p.N + cc] = acc[m][n][j];
        }
  } else if (EPI == 1) {
    const float* bias = is_t ? p.bias_t : p.bias_i;
#pragma unroll
    for (int n = 0; n < 4; ++n) {
      int cc = n0 + wn + n * 16 + lr;
      float bv = bias[cc];
#pragma unroll
      for (int m = 0; m < 4; ++m)
#pragma unroll
        for (int j = 0; j < 4; ++j) {
          int r = m0 + wm + m * 16 + lg * 4 + j;
          p.Cb[(size_t)r * p.N + cc] = f2bu(gelu_t(acc[m][n][j] + bv));
        }
    }
  } else {
    // qkv epilogue: N=6144 -> sel = bx>>4 (q/k/v), h = bx&15
    int sel = bx >> 4, h = bx & 15;
#pragma unroll
    for (int n = 0; n < 4; ++n) {
      int d = wn + n * 16 + lr;
#pragma unroll
      for (int m = 0; m < 4; ++m)
#pragma unroll
        for (int j = 0; j < 4; ++j) {
          int r = m0 + wm + m * 16 + lg * 4 + j;
          float v = acc[m][n][j];
          if (is_t) {
            unsigned short bv = f2bu(v);
            if (sel == 0) p.q_txt[((size_t)h * 512 + r) * 128 + d] = bv;
            else if (sel == 1) p.k_cat[((size_t)h * 2560 + r) * 128 + d] = bv;
            else p.v_cat[((size_t)h * 2560 + r) * 128 + d] = bv;
          } else {
            int s = r - 512;
            if (sel == 2) {
              p.v_cat[((size_t)h * 2560 + r) * 128 + d] = f2bu(v);
            } else {
              float c = p.rope[s * 128 + (d & ~1)];
              float sn = p.rope[s * 128 + (d | 1)];
              float part = __shfl_xor(v, 1);
              float vr = (d & 1) ? v * c + part * sn : v * c - part * sn;
              vr *= p.modb[h * 2048 + s];
              unsigned short bv = f2bu(vr);
              if (sel == 0) p.q_img[((size_t)h * 2048 + s) * 128 + d] = bv;
              else p.k_cat[((size_t)h * 2560 + r) * 128 + d] = bv;
            }
          }
        }
    }
  }
}

// ---------------- fused flash attention (txt blocks 0..3, img 4..19) ----------------
__global__ __launch_bounds__(256) void attn_kernel(
    const unsigned short* __restrict__ q_txt, const unsigned short* __restrict__ q_img,
    const unsigned short* __restrict__ Kc, const unsigned short* __restrict__ Vt,
    unsigned short* __restrict__ O, const float* __restrict__ scales) {
  __shared__ int4 sQ[128 * 16];
  __shared__ int4 sK[64 * 16];  // reused as P after QK phase
  __shared__ int4 sV[128 * 8];
  const int tid = threadIdx.x, w = tid >> 6, l = tid & 63, lr = l & 15, lg = l >> 4;
  const int bx = blockIdx.x, h = blockIdx.y;
  const bool is_t = bx < 4;
  const int orow = is_t ? bx * 128 : 512 + (bx - 4) * 128;
  const float scale = scales[is_t ? 0 : 1];
  const unsigned short* Qp = is_t ? q_txt + ((size_t)h * 512 + bx * 128) * 128
                                  : q_img + ((size_t)h * 2048 + (bx - 4) * 128) * 128;
  const int4* Qg = reinterpret_cast<const int4*>(Qp);
#pragma unroll
  for (int i = 0; i < 8; ++i) {
    int c = i * 256 + tid, row = c >> 4, ch = c & 15;
    sQ[row * 16 + (ch ^ (row & 7))] = Qg[c];
  }
  f32x4 oacc[2][8] = {};
  float m_run[2][4], l_run[2][4];
#pragma unroll
  for (int m = 0; m < 2; ++m)
#pragma unroll
    for (int j = 0; j < 4; ++j) { m_run[m][j] = -1e30f; l_run[m][j] = 0.f; }
  const int4* Kg = reinterpret_cast<const int4*>(Kc + (size_t)h * 2560 * 128);
  const int4* Vg = reinterpret_cast<const int4*>(Vt + (size_t)h * 128 * 2560);
  const short8* pQ = reinterpret_cast<const short8*>(sQ);
  const short8* pK = reinterpret_cast<const short8*>(sK);
  const short8* pV = reinterpret_cast<const short8*>(sV);
  const short8* pP = reinterpret_cast<const short8*>(sK);
  unsigned short* sPb = reinterpret_cast<unsigned short*>(sK);

  for (int kt = 0; kt < 40; ++kt) {
    __syncthreads();
#pragma unroll
    for (int i = 0; i < 4; ++i) {
      int c = i * 256 + tid, row = c >> 4, ch = c & 15;
      sK[row * 16 + (ch ^ (row & 7))] = Kg[(size_t)kt * 1024 + c];
    }
#pragma unroll
    for (int i = 0; i < 4; ++i) {
      int c = i * 256 + tid, row = c >> 3, ch = c & 7;
      sV[row * 8 + (ch ^ (row & 7))] = Vg[(size_t)row * 320 + kt * 8 + ch];
    }
    __syncthreads();
    f32x4 sacc[2][4] = {};
#pragma unroll
    for (int ds = 0; ds < 4; ++ds) {
      short8 aq[2], bk[4];
#pragma unroll
      for (int m = 0; m < 2; ++m) {
        int row = w * 32 + m * 16 + lr;
        aq[m] = pQ[row * 16 + ((ds * 4 + lg) ^ (row & 7))];
      }
#pragma unroll
      for (int n = 0; n < 4; ++n) {
        int row = n * 16 + lr;
        bk[n] = pK[row * 16 + ((ds * 4 + lg) ^ (row & 7))];
      }
#pragma unroll
      for (int m = 0; m < 2; ++m)
#pragma unroll
        for (int n = 0; n < 4; ++n)
          sacc[m][n] = __builtin_amdgcn_mfma_f32_16x16x32_bf16(aq[m], bk[n], sacc[m][n], 0, 0, 0);
    }
    __syncthreads();
    float corr_[2][4];
#pragma unroll
    for (int m = 0; m < 2; ++m)
#pragma unroll
      for (int j = 0; j < 4; ++j) {
        float mx = -1e30f;
#pragma unroll
        for (int n = 0; n < 4; ++n) {
          sacc[m][n][j] *= scale;
          mx = fmaxf(mx, sacc[m][n][j]);
        }
        mx = fmaxf(mx, __shfl_xor(mx, 1));
        mx = fmaxf(mx, __shfl_xor(mx, 2));
        mx = fmaxf(mx, __shfl_xor(mx, 4));
        mx = fmaxf(mx, __shfl_xor(mx, 8));
        float mn = fmaxf(m_run[m][j], mx);
        float corr = __expf(m_run[m][j] - mn);
        m_run[m][j] = mn;
        float rs = 0.f;
#pragma unroll
        for (int n = 0; n < 4; ++n) {
          float pp = __expf(sacc[m][n][j] - mn);
          sacc[m][n][j] = pp;
          rs += pp;
        }
        rs += __shfl_xor(rs, 1);
        rs += __shfl_xor(rs, 2);
        rs += __shfl_xor(rs, 4);
        rs += __shfl_xor(rs, 8);
        l_run[m][j] = l_run[m][j] * corr + rs;
        corr_[m][j] = corr;
      }
#pragma unroll
    for (int m = 0; m < 2; ++m)
#pragma unroll
      for (int n = 0; n < 8; ++n)
#pragma unroll
        for (int j = 0; j < 4; ++j) oacc[m][n][j] *= corr_[m][j];
#pragma unroll
    for (int m = 0; m < 2; ++m)
#pragma unroll
      for (int n = 0; n < 4; ++n)
#pragma unroll
        for (int j = 0; j < 4; ++j) {
          int row = w * 32 + m * 16 + lg * 4 + j;
          int col = n * 16 + lr;
          sPb[row * 64 + (((col >> 3) ^ (row & 7)) << 3) + (col & 7)] = f2bu(sacc[m][n][j]);
        }
#pragma unroll
    for (int kk = 0; kk < 2; ++kk) {
      short8 ap[2], bv[8];
#pragma unroll
      for (int m = 0; m < 2; ++m) {
        int row = w * 32 + m * 16 + lr;
        ap[m] = pP[row * 8 + ((kk * 4 + lg) ^ (row & 7))];
      }
#pragma unroll
      for (int n = 0; n < 8; ++n) {
        int row = n * 16 + lr;
        bv[n] = pV[row * 8 + ((kk * 4 + lg) ^ (row & 7))];
      }
#pragma unroll
      for (int m = 0; m < 2; ++m)
#pragma unroll
        for (int n = 0; n < 8; ++n)
          oacc[m][n] = __builtin_amdgcn_mfma_f32_16x16x32_bf16(ap[m], bv[n], oacc[m][n], 0, 0, 0);
    }
  }
#pragma unroll
  for (int m = 0; m < 2; ++m)
#pragma unroll
    for (int j = 0; j < 4; ++j) {
      float inv = 1.f / l_run[m][j];
      int row = orow + w * 32 + m * 16 + lg * 4 + j;
#pragma unroll
      for (int n = 0; n < 8; ++n)
        O[(size_t)row * 2048 + h * 128 + n * 16 + lr] = f2bu(oacc[m][n][j] * inv);
    }
}

// ---------------- residuals (sum 2 split-K partials) ----------------
__global__ __launch_bounds__(256) void residual1(
    const float4* __restrict__ X, const float4* __restrict__ P0,
    const float4* __restrict__ P1, const float* __restrict__ e,
    float4* __restrict__ out, int total4) {
  int stride = gridDim.x * 256;
  for (int i = blockIdx.x * 256 + threadIdx.x; i < total4; i += stride) {
    int c = (i * 4) & 2047;
    float4 g = *reinterpret_cast<const float4*>(e + 4096 + c);
    float4 x = X[i], p0 = P0[i], p1 = P1[i], o;
    o.x = x.x + g.x * (p0.x + p1.x); o.y = x.y + g.y * (p0.y + p1.y);
    o.z = x.z + g.z * (p0.z + p1.z); o.w = x.w + g.w * (p0.w + p1.w);
    out[i] = o;
  }
}

__global__ __launch_bounds__(256) void residual2(
    const float4* __restrict__ P0, const float4* __restrict__ P1,
    const float* __restrict__ b2, const float* __restrict__ e,
    float4* __restrict__ out, int total4) {
  int stride = gridDim.x * 256;
  for (int i = blockIdx.x * 256 + threadIdx.x; i < total4; i += stride) {
    int c = (i * 4) & 2047;
    float4 g = *reinterpret_cast<const float4*>(e + 10240 + c);
    float4 bb = *reinterpret_cast<const float4*>(b2 + c);
    float4 p0 = P0[i], p1 = P1[i], o = out[i];
    o.x += g.x * (p0.x + p1.x + bb.x); o.y += g.y * (p0.y + p1.y + bb.y);
    o.z += g.z * (p0.z + p1.z + bb.z); o.w += g.w * (p0.w + p1.w + bb.w);
    out[i] = o;
  }
}

extern "C" void kernel_launch(void* const* d_in, const int* in_sizes, int n_in,
                              void* d_out, int out_size, void* d_ws, size_t ws_size,
                              hipStream_t stream) {
  (void)in_sizes; (void)n_in; (void)out_size; (void)ws_size;
  const float* txt = (const float*)d_in[0];
  const float* img = (const float*)d_in[1];
  const float* vec = (const float*)d_in[2];
  const float* rope = (const float*)d_in[3];
  const float* sol_t = (const float*)d_in[4];
  const float* sol_s = (const float*)d_in[5];
  const float* ada_img_w = (const float*)d_in[6];
  const float* ada_img_b = (const float*)d_in[7];
  const float* ada_img_nw = (const float*)d_in[8];
  const float* ada_txt_w = (const float*)d_in[9];
  const float* ada_txt_b = (const float*)d_in[10];
  const float* ada_txt_nw = (const float*)d_in[11];
  const float* txt_qkv_w = (const float*)d_in[12];
  const float* img_qkv_w = (const float*)d_in[13];
  const float* txt_out_w = (const float*)d_in[14];
  const float* img_out_w = (const float*)d_in[15];
  const float* mod_w = (const float*)d_in[16];
  const float* mod_b = (const float*)d_in[17];
  const float* img_n2_w = (const float*)d_in[18];
  const float* txt_n2_w = (const float*)d_in[19];
  const float* img_fc1_w = (const float*)d_in[20];
  const float* img_fc1_b = (const float*)d_in[21];
  const float* img_fc2_w = (const float*)d_in[22];
  const float* img_fc2_b = (const float*)d_in[23];
  const float* txt_fc1_w = (const float*)d_in[24];
  const float* txt_fc1_b = (const float*)d_in[25];
  const float* txt_fc2_w = (const float*)d_in[26];
  const float* txt_fc2_b = (const float*)d_in[27];
  float* out = (float*)d_out;
  float* out_img = out + (size_t)512 * 2048;
  char* ws = (char*)d_ws;

  const size_t MB = 1 << 20;
  float* silu_vec = (float*)(ws + 0);
  float* scales = (float*)(ws + 8192);
  float* modb = (float*)(ws + 16384);
  float* e_img = (float*)(ws + 147456);
  float* e_txt = (float*)(ws + 196608);
  unsigned short* wt0 = (unsigned short*)(ws + 1 * MB);    // 32MB txt weights
  unsigned short* wt1 = (unsigned short*)(ws + 33 * MB);   // 32MB img weights
  unsigned short* actA = (unsigned short*)(ws + 65 * MB);  // [2560][2048] bf16, 10MB
  char* attn_base = ws + 75 * MB;                          // 50MB region
  unsigned short* q_txt = (unsigned short*)(attn_base);              // 2MB
  unsigned short* q_img = (unsigned short*)(attn_base + 2 * MB);     // 8MB
  unsigned short* k_cat = (unsigned short*)(attn_base + 10 * MB);    // 10MB
  unsigned short* v_cat = (unsigned short*)(attn_base + 20 * MB);    // 10MB
  unsigned short* vT = (unsigned short*)(attn_base + 30 * MB);       // 10MB
  unsigned short* ao = (unsigned short*)(attn_base + 40 * MB);       // [2560][2048] 10MB
  unsigned short* actB = (unsigned short*)attn_base;  // [2560][8192] bf16 40MB (MLP phase; overlays q/k/v/vT)
  float* Cbuf = (float*)(ws + 125 * MB);  // 2 partials x [2560][2048] f32 = 40MB
  const size_t PSTR = (size_t)2560 * 2048;  // partial z-stride (elements)

  prep_small<<<1, 256, 0, stream>>>(vec, sol_t, silu_vec, scales);
  mod_kernel<<<128, 256, 0, stream>>>(sol_s, mod_w, mod_b, modb);
  ada_gemv<<<dim3(192, 2), 256, 0, stream>>>(silu_vec, ada_img_w, ada_img_b,
                                             ada_txt_w, ada_txt_b, e_img, e_txt);
  // norm1 -> merged actA
  rmsmod_kernel<<<512, 256, 0, stream>>>(txt, ada_txt_nw, e_txt, 0, 2048, actA);
  rmsmod_kernel<<<2048, 256, 0, stream>>>(img, ada_img_nw, e_img, 0, 2048,
                                          actA + (size_t)512 * 2048);
  // qkv (merged, fused rope/mod/concat epilogue)
  transpose_w<<<dim3(192, 64), dim3(32, 8), 0, stream>>>(txt_qkv_w, wt0, 2048, 6144);
  transpose_w<<<dim3(192, 64), dim3(32, 8), 0, stream>>>(img_qkv_w, wt1, 2048, 6144);
  {
    GemmP p = {actA, wt0, wt1, nullptr, nullptr, nullptr, nullptr,
               rope, modb, q_txt, q_img, k_cat, v_cat, 4, 6144, 2048, 1};
    gemm2<2><<<dim3(48, 20, 1), 256, 0, stream>>>(p);
  }
  transpose_v<<<dim3(80, 4, 16), dim3(32, 8), 0, stream>>>(v_cat, vT);
  attn_kernel<<<dim3(20, 16), 256, 0, stream>>>(q_txt, q_img, k_cat, vT, ao, scales);
  // out projection (merged, split-K=2) + residual
  transpose_w<<<dim3(64, 64), dim3(32, 8), 0, stream>>>(txt_out_w, wt0, 2048, 2048);
  transpose_w<<<dim3(64, 64), dim3(32, 8), 0, stream>>>(img_out_w, wt1, 2048, 2048);
  {
    GemmP p = {ao, wt0, wt1, Cbuf, nullptr, nullptr, nullptr,
               nullptr, nullptr, nullptr, nullptr, nullptr, nullptr, 4, 2048, 2048, 2};
    gemm2<0><<<dim3(16, 20, 2), 256, 0, stream>>>(p);
  }
  residual1<<<512, 256, 0, stream>>>((const float4*)txt, (const float4*)Cbuf,
                                     (const float4*)(Cbuf + PSTR), e_txt,
                                     (float4*)out, 512 * 2048 / 4);
  residual1<<<1024, 256, 0, stream>>>((const float4*)img,
                                      (const float4*)(Cbuf + (size_t)512 * 2048),
                                      (const float4*)(Cbuf + PSTR + (size_t)512 * 2048), e_img,
                                      (float4*)out_img, 2048 * 2048 / 4);
  // norm2 -> actA
  rmsmod_kernel<<<512, 256, 0, stream>>>(out, txt_n2_w, e_txt, 6144, 8192, actA);
  rmsmod_kernel<<<2048, 256, 0, stream>>>(out_img, img_n2_w, e_img, 6144, 8192,
                                          actA + (size_t)512 * 2048);
  // fc1 (merged, fused gelu+bias) -> actB bf16 [2560][8192]
  transpose_w<<<dim3(256, 64), dim3(32, 8), 0, stream>>>(txt_fc1_w, wt0, 2048, 8192);
  transpose_w<<<dim3(256, 64), dim3(32, 8), 0, stream>>>(img_fc1_w, wt1, 2048, 8192);
  {
    GemmP p = {actA, wt0, wt1, nullptr, actB, txt_fc1_b, img_fc1_b,
               nullptr, nullptr, nullptr, nullptr, nullptr, nullptr, 4, 8192, 2048, 1};
    gemm2<1><<<dim3(64, 20, 1), 256, 0, stream>>>(p);
  }
  // fc2 (merged, split-K=2) + residual
  transpose_w<<<dim3(64, 256), dim3(32, 8), 0, stream>>>(txt_fc2_w, wt0, 8192, 2048);
  transpose_w<<<dim3(64, 256), dim3(32, 8), 0, stream>>>(img_fc2_w, wt1, 8192, 2048);
  {
    GemmP p = {actB, wt0, wt1, Cbuf, nullptr, nullptr, nullptr,
               nullptr, nullptr, nullptr, nullptr, nullptr, nullptr, 4, 2048, 8192, 2};
    gemm2<0><<<dim3(16, 20, 2), 256, 0, stream>>>(p);
  }
  residual2<<<512, 256, 0, stream>>>((const float4*)Cbuf, (const float4*)(Cbuf + PSTR),
                                     txt_fc2_b, e_txt, (float4*)out, 512 * 2048 / 4);
  residual2<<<1024, 256, 0, stream>>>((const float4*)(Cbuf + (size_t)512 * 2048),
                                      (const float4*)(Cbuf + PSTR + (size_t)512 * 2048),
                                      img_fc2_b, e_img, (float4*)out_img, 2048 * 2048 / 4);
}

// Round 4
// 919.148 us; speedup vs baseline: 1.2617x; 1.0787x over previous
//
#include <hip/hip_runtime.h>

typedef short short8 __attribute__((ext_vector_type(8)));
typedef float f32x4 __attribute__((ext_vector_type(4)));

__device__ __forceinline__ unsigned short f2bu(float f) {
  unsigned u = __builtin_bit_cast(unsigned, f);
  u += 0x7fffu + ((u >> 16) & 1u);
  return (unsigned short)(u >> 16);
}

__device__ __forceinline__ float b2f(unsigned short b) {
  unsigned u = (unsigned)b << 16;
  return __builtin_bit_cast(float, u);
}

__device__ __forceinline__ float gelu_t(float x) {
  float x3 = x * x * x;
  float t = tanhf(0.7978845608028654f * (x + 0.044715f * x3));
  return 0.5f * x * (1.f + t);
}

__device__ __forceinline__ void gload16(const void* g, void* l) {
  __builtin_amdgcn_global_load_lds(
      (const __attribute__((address_space(1))) void*)g,
      (__attribute__((address_space(3))) void*)l, 16, 0, 0);
}

// ---------------- small prep ----------------
__global__ __launch_bounds__(256) void prep_small(
    const float* __restrict__ vec, const float* __restrict__ sol_t,
    float* __restrict__ silu_vec, float* __restrict__ scales) {
  __shared__ float red[4];
  int t = threadIdx.x;
  float v = (t < 64) ? sol_t[t] : 0.f;
#pragma unroll
  for (int o = 32; o > 0; o >>= 1) v += __shfl_down(v, o);
  if ((t & 63) == 0) red[t >> 6] = v;
  __syncthreads();
  if (t == 0) {
    float m = (red[0] + red[1] + red[2] + red[3]) * (1.f / 64.f);
    m = fmaxf(m, 0.1f);
    const float sc = 0.08838834764831845f;  // 128^-0.5
    scales[0] = sc;
    scales[1] = sc / m;  // s_eff^2 folded into score scale
  }
  for (int k = t; k < 2048; k += 256) {
    float x = vec[k];
    silu_vec[k] = x / (1.f + expf(-x));
  }
}

__global__ __launch_bounds__(256) void mod_kernel(
    const float* __restrict__ S, const float* __restrict__ mw,
    const float* __restrict__ mb, float* __restrict__ modb) {
  int idx = blockIdx.x * 256 + threadIdx.x;  // 16*2048
  int h = idx >> 11, n = idx & 2047;
  int y = n >> 5, x = n & 31;
  float cy = (y + 0.5f) * 0.125f - 0.5f;
  float cx = (x + 0.5f) * 0.25f - 0.5f;
  int y0 = (int)floorf(cy); float fy = cy - (float)y0;
  int x0 = (int)floorf(cx); float fx = cx - (float)x0;
  int y0c = min(max(y0, 0), 7), y1c = min(max(y0 + 1, 0), 7);
  int x0c = min(max(x0, 0), 7), x1c = min(max(x0 + 1, 0), 7);
  float v = (1.f - fy) * ((1.f - fx) * S[y0c * 8 + x0c] + fx * S[y0c * 8 + x1c]) +
            fy * ((1.f - fx) * S[y1c * 8 + x0c] + fx * S[y1c * 8 + x1c]);
  float t = v * mw[h] + mb[h];
  t = fminf(fmaxf(t, -2.f), 2.f);
  modb[idx] = expf(t);
}

__global__ __launch_bounds__(256) void ada_gemv(
    const float* __restrict__ sv,
    const float* __restrict__ Wi, const float* __restrict__ bi,
    const float* __restrict__ Wt, const float* __restrict__ bt,
    float* __restrict__ ei, float* __restrict__ et) {
  __shared__ float red[4][64];
  const float* W = blockIdx.y ? Wt : Wi;
  const float* bb = blockIdx.y ? bt : bi;
  float* e = blockIdx.y ? et : ei;
  int jl = threadIdx.x & 63, ks = threadIdx.x >> 6;
  int j = blockIdx.x * 64 + jl;
  float acc = 0.f;
  int k0 = ks * 512;
#pragma unroll 4
  for (int k = 0; k < 512; ++k) acc += sv[k0 + k] * W[(size_t)(k0 + k) * 12288 + j];
  red[ks][jl] = acc;
  __syncthreads();
  if (ks == 0) e[j] = red[0][jl] + red[1][jl] + red[2][jl] + red[3][jl] + bb[j];
}

// ---------------- RMSNorm + adaLN modulate -> bf16 ----------------
__global__ __launch_bounds__(256) void rmsmod_kernel(
    const float* __restrict__ X, const float* __restrict__ nw,
    const float* __restrict__ e, int sh_off, int sc_off,
    unsigned short* __restrict__ out) {
  __shared__ float red[4];
  int r = blockIdx.x, t = threadIdx.x;
  const float4* xr = reinterpret_cast<const float4*>(X + (size_t)r * 2048);
  float4 v0 = xr[t * 2], v1 = xr[t * 2 + 1];
  float ss = v0.x * v0.x + v0.y * v0.y + v0.z * v0.z + v0.w * v0.w +
             v1.x * v1.x + v1.y * v1.y + v1.z * v1.z + v1.w * v1.w;
#pragma unroll
  for (int o = 32; o > 0; o >>= 1) ss += __shfl_down(ss, o);
  if ((t & 63) == 0) red[t >> 6] = ss;
  __syncthreads();
  float rinv = rsqrtf((red[0] + red[1] + red[2] + red[3]) * (1.f / 2048.f) + 1e-6f);
  int c0 = t * 8;
  float xv[8] = {v0.x, v0.y, v0.z, v0.w, v1.x, v1.y, v1.z, v1.w};
  short8 ov;
#pragma unroll
  for (int i = 0; i < 8; ++i) {
    int c = c0 + i;
    float y = xv[i] * rinv * nw[c] * (1.f + e[sc_off + c]) + e[sh_off + c];
    ov[i] = (short)f2bu(y);
  }
  *reinterpret_cast<short8*>(out + (size_t)r * 2048 + c0) = ov;
}

// ---------------- weight transpose+convert ----------------
__global__ __launch_bounds__(256) void transpose_w(
    const float* __restrict__ W, unsigned short* __restrict__ Bt, int K, int N) {
  __shared__ float tile[32][33];
  int n0 = blockIdx.x * 32, k0 = blockIdx.y * 32;
  int tx = threadIdx.x, ty = threadIdx.y;
#pragma unroll
  for (int j = 0; j < 32; j += 8)
    tile[ty + j][tx] = W[(size_t)(k0 + ty + j) * N + n0 + tx];
  __syncthreads();
#pragma unroll
  for (int j = 0; j < 32; j += 8)
    Bt[(size_t)(n0 + ty + j) * K + k0 + tx] = f2bu(tile[tx][ty + j]);
}

__global__ __launch_bounds__(256) void transpose_v(
    const unsigned short* __restrict__ V, unsigned short* __restrict__ Vt) {
  __shared__ unsigned short tile[32][33];
  int h = blockIdx.z;
  int s0 = blockIdx.x * 32, d0 = blockIdx.y * 32;
  int tx = threadIdx.x, ty = threadIdx.y;
  const unsigned short* src = V + (size_t)h * 2560 * 128;
  unsigned short* dst = Vt + (size_t)h * 128 * 2560;
#pragma unroll
  for (int j = 0; j < 32; j += 8)
    tile[ty + j][tx] = src[(size_t)(s0 + ty + j) * 128 + d0 + tx];
  __syncthreads();
#pragma unroll
  for (int j = 0; j < 32; j += 8)
    dst[(size_t)(d0 + ty + j) * 2560 + s0 + tx] = tile[tx][ty + j];
}

// ---------------- batched GEMM (txt rows 0..511, img rows 512..2559) ----------------
struct GemmP {
  const unsigned short *A, *Bt_t, *Bt_i;
  float* C;
  unsigned short* Cb;
  const float *bias_t, *bias_i;
  const float *rope, *modb;
  unsigned short *q_txt, *q_img, *k_cat, *v_cat;
  int Mb_t;
  int N, K, KS;
};

template <int EPI>
__global__ __launch_bounds__(256) void gemm2(GemmP p) {
  __shared__ int4 sA[128 * 8];
  __shared__ int4 sB[128 * 8];
  const int NB = gridDim.x, MBT = gridDim.y;
  int nwg = NB * MBT;
  int orig = blockIdx.y * NB + blockIdx.x;
  int qq = nwg >> 3, rr = nwg & 7, xcd = orig & 7, base = orig >> 3;
  int sw = (xcd < rr ? xcd * (qq + 1) : rr * (qq + 1) + (xcd - rr) * qq) + base;
  int bx = sw / MBT, by = sw % MBT;
  const bool is_t = by < p.Mb_t;
  const unsigned short* Bt = is_t ? p.Bt_t : p.Bt_i;
  const int m0 = by * 128, n0 = bx * 128;
  const int z = blockIdx.z;
  const int Kz = p.K / p.KS, kbeg = z * Kz, kend = kbeg + Kz;
  const int tid = threadIdx.x;
  const int w = tid >> 6, l = tid & 63, lr = l & 15, lg = l >> 4;
  const int wm = (w >> 1) * 64, wn = (w & 1) * 64;
  f32x4 acc[4][4] = {};
  const int4* Ag = reinterpret_cast<const int4*>(p.A);
  const int4* Bg = reinterpret_cast<const int4*>(Bt);
  const int K8 = p.K >> 3;
  const short8* pA = reinterpret_cast<const short8*>(sA);
  const short8* pB = reinterpret_cast<const short8*>(sB);
  int srow[4], sch[4];
#pragma unroll
  for (int i = 0; i < 4; ++i) {
    int s = i * 256 + tid;
    srow[i] = s >> 3;
    sch[i] = (s & 7) ^ (srow[i] & 7);
  }
  for (int k0 = kbeg; k0 < kend; k0 += 64) {
    __syncthreads();
    int kc = k0 >> 3;
#pragma unroll
    for (int i = 0; i < 4; ++i) {
      gload16(&Ag[(size_t)(m0 + srow[i]) * K8 + kc + sch[i]], &sA[i * 256 + w * 64]);
      gload16(&Bg[(size_t)(n0 + srow[i]) * K8 + kc + sch[i]], &sB[i * 256 + w * 64]);
    }
    __syncthreads();
#pragma unroll
    for (int kk = 0; kk < 2; ++kk) {
      short8 af[4], bf[4];
#pragma unroll
      for (int m = 0; m < 4; ++m) {
        int row = wm + m * 16 + lr;
        af[m] = pA[row * 8 + ((kk * 4 + lg) ^ (row & 7))];
      }
#pragma unroll
      for (int n = 0; n < 4; ++n) {
        int row = wn + n * 16 + lr;
        bf[n] = pB[row * 8 + ((kk * 4 + lg) ^ (row & 7))];
      }
#pragma unroll
      for (int m = 0; m < 4; ++m)
#pragma unroll
        for (int n = 0; n < 4; ++n)
          acc[m][n] = __builtin_amdgcn_mfma_f32_16x16x32_bf16(af[m], bf[n], acc[m][n], 0, 0, 0);
    }
  }
  if (EPI == 0) {
    float* C = p.C + (size_t)z * MBT * 128 * p.N;
#pragma unroll
    for (int m = 0; m < 4; ++m)
#pragma unroll
      for (int n = 0; n < 4; ++n)
#pragma unroll
        for (int j = 0; j < 4; ++j) {
          int r = m0 + wm + m * 16 + lg * 4 + j;
          int cc = n0 + wn + n * 16 + lr;
          C[(size_t)r * p.N + cc] = acc[m][n][j];
        }
  } else if (EPI == 1) {
    const float* bias = is_t ? p.bias_t : p.bias_i;
#pragma unroll
    for (int n = 0; n < 4; ++n) {
      int cc = n0 + wn + n * 16 + lr;
      float bv = bias[cc];
#pragma unroll
      for (int m = 0; m < 4; ++m)
#pragma unroll
        for (int j = 0; j < 4; ++j) {
          int r = m0 + wm + m * 16 + lg * 4 + j;
          p.Cb[(size_t)r * p.N + cc] = f2bu(gelu_t(acc[m][n][j] + bv));
        }
    }
  } else {
    int sel = bx >> 4, h = bx & 15;
#pragma unroll
    for (int n = 0; n < 4; ++n) {
      int d = wn + n * 16 + lr;
#pragma unroll
      for (int m = 0; m < 4; ++m)
#pragma unroll
        for (int j = 0; j < 4; ++j) {
          int r = m0 + wm + m * 16 + lg * 4 + j;
          float v = acc[m][n][j];
          if (is_t) {
            unsigned short bv = f2bu(v);
            if (sel == 0) p.q_txt[((size_t)h * 512 + r) * 128 + d] = bv;
            else if (sel == 1) p.k_cat[((size_t)h * 2560 + r) * 128 + d] = bv;
            else p.v_cat[((size_t)h * 2560 + r) * 128 + d] = bv;
          } else {
            int s = r - 512;
            if (sel == 2) {
              p.v_cat[((size_t)h * 2560 + r) * 128 + d] = f2bu(v);
            } else {
              float c = p.rope[s * 128 + (d & ~1)];
              float sn = p.rope[s * 128 + (d | 1)];
              float part = __shfl_xor(v, 1);
              float vr = (d & 1) ? v * c + part * sn : v * c - part * sn;
              vr *= p.modb[h * 2048 + s];
              unsigned short bv = f2bu(vr);
              if (sel == 0) p.q_img[((size_t)h * 2048 + s) * 128 + d] = bv;
              else p.k_cat[((size_t)h * 2560 + r) * 128 + d] = bv;
            }
          }
        }
    }
  }
}

// ---------------- split-KV flash attention ----------------
// grid (20, 16, 4): bx = q-block (txt 0..3, img 4..19), h, z = KV chunk (10 tiles each).
// Writes unnormalized bf16 partial O + f32 (m,l) stats; attn_merge combines.
__global__ __launch_bounds__(256) void attn_kernel(
    const unsigned short* __restrict__ q_txt, const unsigned short* __restrict__ q_img,
    const unsigned short* __restrict__ Kc, const unsigned short* __restrict__ Vt,
    unsigned short* __restrict__ Op, float* __restrict__ ml,
    const float* __restrict__ scales) {
  __shared__ int4 sK[64 * 16];   // [64 kv][128 d] bf16
  __shared__ int4 sV[128 * 8];   // [128 d][64 kv] bf16
  __shared__ int4 sP[128 * 8];   // [128 q][64 kv] bf16
  const int tid = threadIdx.x, w = tid >> 6, l = tid & 63, lr = l & 15, lg = l >> 4;
  const int bx = blockIdx.x, h = blockIdx.y, z = blockIdx.z;
  const bool is_t = bx < 4;
  const int orow = is_t ? bx * 128 : 512 + (bx - 4) * 128;
  const float scale = scales[is_t ? 0 : 1];
  const unsigned short* Qp = is_t ? q_txt + ((size_t)h * 512 + bx * 128) * 128
                                  : q_img + ((size_t)h * 2048 + (bx - 4) * 128) * 128;
  // Q fragments in registers: aq[m][ds] = Q[w*32+m*16+lr][ds*32 + lg*8 .. +7]
  short8 aq[2][4];
#pragma unroll
  for (int m = 0; m < 2; ++m)
#pragma unroll
    for (int ds = 0; ds < 4; ++ds) {
      int row = w * 32 + m * 16 + lr;
      aq[m][ds] = *reinterpret_cast<const short8*>(Qp + (size_t)row * 128 + ds * 32 + lg * 8);
    }
  f32x4 oacc[2][8] = {};
  float m_run[2][4], l_run[2][4];
#pragma unroll
  for (int m = 0; m < 2; ++m)
#pragma unroll
    for (int j = 0; j < 4; ++j) { m_run[m][j] = -1e30f; l_run[m][j] = 0.f; }
  const int4* Kg = reinterpret_cast<const int4*>(Kc + (size_t)h * 2560 * 128);
  const int4* Vg = reinterpret_cast<const int4*>(Vt + (size_t)h * 128 * 2560);
  const short8* pK = reinterpret_cast<const short8*>(sK);
  const short8* pV = reinterpret_cast<const short8*>(sV);
  const short8* pP = reinterpret_cast<const short8*>(sP);
  unsigned short* sPb = reinterpret_cast<unsigned short*>(sP);
  // staging geometry (linear LDS dest, XOR-swizzled global source)
  int krow[4], kch[4], vrow[4], vch[4];
#pragma unroll
  for (int i = 0; i < 4; ++i) {
    int s = i * 256 + tid;
    krow[i] = s >> 4; kch[i] = (s & 15) ^ (krow[i] & 7);
    vrow[i] = s >> 3; vch[i] = (s & 7) ^ (vrow[i] & 7);
  }
  for (int kt = z * 10; kt < z * 10 + 10; ++kt) {
    __syncthreads();
#pragma unroll
    for (int i = 0; i < 4; ++i) {
      gload16(&Kg[(size_t)(kt * 64 + krow[i]) * 16 + kch[i]], &sK[i * 256 + w * 64]);
      gload16(&Vg[(size_t)vrow[i] * 320 + kt * 8 + vch[i]], &sV[i * 256 + w * 64]);
    }
    __syncthreads();
    f32x4 sacc[2][4] = {};
    __builtin_amdgcn_s_setprio(1);
#pragma unroll
    for (int ds = 0; ds < 4; ++ds) {
      short8 bk[4];
#pragma unroll
      for (int n = 0; n < 4; ++n) {
        int row = n * 16 + lr;
        bk[n] = pK[row * 16 + ((ds * 4 + lg) ^ (row & 7))];
      }
#pragma unroll
      for (int m = 0; m < 2; ++m)
#pragma unroll
        for (int n = 0; n < 4; ++n)
          sacc[m][n] = __builtin_amdgcn_mfma_f32_16x16x32_bf16(aq[m][ds], bk[n], sacc[m][n], 0, 0, 0);
    }
    __builtin_amdgcn_s_setprio(0);
    float corr_[2][4];
#pragma unroll
    for (int m = 0; m < 2; ++m)
#pragma unroll
      for (int j = 0; j < 4; ++j) {
        float mx = -1e30f;
#pragma unroll
        for (int n = 0; n < 4; ++n) {
          sacc[m][n][j] *= scale;
          mx = fmaxf(mx, sacc[m][n][j]);
        }
        mx = fmaxf(mx, __shfl_xor(mx, 1));
        mx = fmaxf(mx, __shfl_xor(mx, 2));
        mx = fmaxf(mx, __shfl_xor(mx, 4));
        mx = fmaxf(mx, __shfl_xor(mx, 8));
        float mn = fmaxf(m_run[m][j], mx);
        float corr = __expf(m_run[m][j] - mn);
        m_run[m][j] = mn;
        float rs = 0.f;
#pragma unroll
        for (int n = 0; n < 4; ++n) {
          float pp = __expf(sacc[m][n][j] - mn);
          sacc[m][n][j] = pp;
          rs += pp;
        }
        rs += __shfl_xor(rs, 1);
        rs += __shfl_xor(rs, 2);
        rs += __shfl_xor(rs, 4);
        rs += __shfl_xor(rs, 8);
        l_run[m][j] = l_run[m][j] * corr + rs;
        corr_[m][j] = corr;
      }
#pragma unroll
    for (int m = 0; m < 2; ++m)
#pragma unroll
      for (int n = 0; n < 8; ++n)
#pragma unroll
        for (int j = 0; j < 4; ++j) oacc[m][n][j] *= corr_[m][j];
    // write P (each wave owns its own 32 q-rows; no cross-wave P dependency)
#pragma unroll
    for (int m = 0; m < 2; ++m)
#pragma unroll
      for (int n = 0; n < 4; ++n)
#pragma unroll
        for (int j = 0; j < 4; ++j) {
          int row = w * 32 + m * 16 + lg * 4 + j;
          int col = n * 16 + lr;
          sPb[row * 64 + (((col >> 3) ^ (row & 7)) << 3) + (col & 7)] = f2bu(sacc[m][n][j]);
        }
    __builtin_amdgcn_s_setprio(1);
#pragma unroll
    for (int kk = 0; kk < 2; ++kk) {
      short8 ap[2], bv[8];
#pragma unroll
      for (int m = 0; m < 2; ++m) {
        int row = w * 32 + m * 16 + lr;
        ap[m] = pP[row * 8 + ((kk * 4 + lg) ^ (row & 7))];
      }
#pragma unroll
      for (int n = 0; n < 8; ++n) {
        int row = n * 16 + lr;
        bv[n] = pV[row * 8 + ((kk * 4 + lg) ^ (row & 7))];
      }
#pragma unroll
      for (int m = 0; m < 2; ++m)
#pragma unroll
        for (int n = 0; n < 8; ++n)
          oacc[m][n] = __builtin_amdgcn_mfma_f32_16x16x32_bf16(ap[m], bv[n], oacc[m][n], 0, 0, 0);
    }
    __builtin_amdgcn_s_setprio(0);
  }
  // store unnormalized partial O (bf16) + stats (f32) for merge
  const size_t zbase = (size_t)z * 40960 + (size_t)h * 2560 + orow;
#pragma unroll
  for (int m = 0; m < 2; ++m)
#pragma unroll
    for (int j = 0; j < 4; ++j) {
      int row = w * 32 + m * 16 + lg * 4 + j;
#pragma unroll
      for (int n = 0; n < 8; ++n)
        Op[(zbase + row) * 128 + n * 16 + lr] = f2bu(oacc[m][n][j]);
      if (lr == 0) {
        ml[(zbase + row) * 2] = m_run[m][j];
        ml[(zbase + row) * 2 + 1] = l_run[m][j];
      }
    }
}

// merge 4 KV-chunk partials (LSE combine) -> ao[r][h*128+d] bf16
__global__ __launch_bounds__(256) void attn_merge(
    const unsigned short* __restrict__ Op, const float* __restrict__ ml,
    unsigned short* __restrict__ ao) {
  int gid = blockIdx.x * 256 + threadIdx.x;  // 40960 rows * 32 threads
  int rid = gid >> 5, d0 = (gid & 31) * 4;
  int h = rid >> 11;          // rid / 2560? no: 2560 not pow2 -> compute properly
  h = rid / 2560;
  int r = rid - h * 2560;
  float M = -1e30f;
#pragma unroll
  for (int z = 0; z < 4; ++z) M = fmaxf(M, ml[((size_t)z * 40960 + rid) * 2]);
  float L = 0.f, o0 = 0.f, o1 = 0.f, o2 = 0.f, o3 = 0.f;
#pragma unroll
  for (int z = 0; z < 4; ++z) {
    size_t sidx = (size_t)z * 40960 + rid;
    float mz = ml[sidx * 2], lz = ml[sidx * 2 + 1];
    float wgt = __expf(mz - M);
    L += wgt * lz;
    ushort4 v = *reinterpret_cast<const ushort4*>(Op + sidx * 128 + d0);
    o0 += wgt * b2f(v.x); o1 += wgt * b2f(v.y);
    o2 += wgt * b2f(v.z); o3 += wgt * b2f(v.w);
  }
  float inv = 1.f / L;
  ushort4 ov;
  ov.x = f2bu(o0 * inv); ov.y = f2bu(o1 * inv);
  ov.z = f2bu(o2 * inv); ov.w = f2bu(o3 * inv);
  *reinterpret_cast<ushort4*>(ao + (size_t)r * 2048 + h * 128 + d0) = ov;
}

// ---------------- residuals (sum 2 split-K partials) ----------------
__global__ __launch_bounds__(256) void residual1(
    const float4* __restrict__ X, const float4* __restrict__ P0,
    const float4* __restrict__ P1, const float* __restrict__ e,
    float4* __restrict__ out, int total4) {
  int stride = gridDim.x * 256;
  for (int i = blockIdx.x * 256 + threadIdx.x; i < total4; i += stride) {
    int c = (i * 4) & 2047;
    float4 g = *reinterpret_cast<const float4*>(e + 4096 + c);
    float4 x = X[i], p0 = P0[i], p1 = P1[i], o;
    o.x = x.x + g.x * (p0.x + p1.x); o.y = x.y + g.y * (p0.y + p1.y);
    o.z = x.z + g.z * (p0.z + p1.z); o.w = x.w + g.w * (p0.w + p1.w);
    out[i] = o;
  }
}

__global__ __launch_bounds__(256) void residual2(
    const float4* __restrict__ P0, const float4* __restrict__ P1,
    const float* __restrict__ b2, const float* __restrict__ e,
    float4* __restrict__ out, int total4) {
  int stride = gridDim.x * 256;
  for (int i = blockIdx.x * 256 + threadIdx.x; i < total4; i += stride) {
    int c = (i * 4) & 2047;
    float4 g = *reinterpret_cast<const float4*>(e + 10240 + c);
    float4 bb = *reinterpret_cast<const float4*>(b2 + c);
    float4 p0 = P0[i], p1 = P1[i], o = out[i];
    o.x += g.x * (p0.x + p1.x + bb.x); o.y += g.y * (p0.y + p1.y + bb.y);
    o.z += g.z * (p0.z + p1.z + bb.z); o.w += g.w * (p0.w + p1.w + bb.w);
    out[i] = o;
  }
}

extern "C" void kernel_launch(void* const* d_in, const int* in_sizes, int n_in,
                              void* d_out, int out_size, void* d_ws, size_t ws_size,
                              hipStream_t stream) {
  (void)in_sizes; (void)n_in; (void)out_size; (void)ws_size;
  const float* txt = (const float*)d_in[0];
  const float* img = (const float*)d_in[1];
  const float* vec = (const float*)d_in[2];
  const float* rope = (const float*)d_in[3];
  const float* sol_t = (const float*)d_in[4];
  const float* sol_s = (const float*)d_in[5];
  const float* ada_img_w = (const float*)d_in[6];
  const float* ada_img_b = (const float*)d_in[7];
  const float* ada_img_nw = (const float*)d_in[8];
  const float* ada_txt_w = (const float*)d_in[9];
  const float* ada_txt_b = (const float*)d_in[10];
  const float* ada_txt_nw = (const float*)d_in[11];
  const float* txt_qkv_w = (const float*)d_in[12];
  const float* img_qkv_w = (const float*)d_in[13];
  const float* txt_out_w = (const float*)d_in[14];
  const float* img_out_w = (const float*)d_in[15];
  const float* mod_w = (const float*)d_in[16];
  const float* mod_b = (const float*)d_in[17];
  const float* img_n2_w = (const float*)d_in[18];
  const float* txt_n2_w = (const float*)d_in[19];
  const float* img_fc1_w = (const float*)d_in[20];
  const float* img_fc1_b = (const float*)d_in[21];
  const float* img_fc2_w = (const float*)d_in[22];
  const float* img_fc2_b = (const float*)d_in[23];
  const float* txt_fc1_w = (const float*)d_in[24];
  const float* txt_fc1_b = (const float*)d_in[25];
  const float* txt_fc2_w = (const float*)d_in[26];
  const float* txt_fc2_b = (const float*)d_in[27];
  float* out = (float*)d_out;
  float* out_img = out + (size_t)512 * 2048;
  char* ws = (char*)d_ws;

  const size_t MB = 1 << 20;
  float* silu_vec = (float*)(ws + 0);
  float* scales = (float*)(ws + 8192);
  float* modb = (float*)(ws + 16384);
  float* e_img = (float*)(ws + 147456);
  float* e_txt = (float*)(ws + 196608);
  unsigned short* wt0 = (unsigned short*)(ws + 1 * MB);    // 32MB txt weights
  unsigned short* wt1 = (unsigned short*)(ws + 33 * MB);   // 32MB img weights
  // attention partials overlay the weight region (dead between qkv-gemm and out-proj transpose)
  unsigned short* Opart = (unsigned short*)(ws + 1 * MB);  // 4*40960*128 bf16 = 40MB
  float* mlbuf = (float*)(ws + 42 * MB);                   // 4*40960*2 f32 = 1.25MB
  unsigned short* actA = (unsigned short*)(ws + 65 * MB);  // [2560][2048] bf16, 10MB
  char* attn_base = ws + 75 * MB;                          // 50MB region
  unsigned short* q_txt = (unsigned short*)(attn_base);              // 2MB
  unsigned short* q_img = (unsigned short*)(attn_base + 2 * MB);     // 8MB
  unsigned short* k_cat = (unsigned short*)(attn_base + 10 * MB);    // 10MB
  unsigned short* v_cat = (unsigned short*)(attn_base + 20 * MB);    // 10MB
  unsigned short* vT = (unsigned short*)(attn_base + 30 * MB);       // 10MB
  unsigned short* ao = (unsigned short*)(attn_base + 40 * MB);       // [2560][2048] 10MB
  unsigned short* actB = (unsigned short*)attn_base;  // [2560][8192] bf16 40MB (MLP phase)
  float* Cbuf = (float*)(ws + 125 * MB);  // 2 partials x [2560][2048] f32 = 40MB
  const size_t PSTR = (size_t)2560 * 2048;

  prep_small<<<1, 256, 0, stream>>>(vec, sol_t, silu_vec, scales);
  mod_kernel<<<128, 256, 0, stream>>>(sol_s, mod_w, mod_b, modb);
  ada_gemv<<<dim3(192, 2), 256, 0, stream>>>(silu_vec, ada_img_w, ada_img_b,
                                             ada_txt_w, ada_txt_b, e_img, e_txt);
  // norm1 -> merged actA
  rmsmod_kernel<<<512, 256, 0, stream>>>(txt, ada_txt_nw, e_txt, 0, 2048, actA);
  rmsmod_kernel<<<2048, 256, 0, stream>>>(img, ada_img_nw, e_img, 0, 2048,
                                          actA + (size_t)512 * 2048);
  // qkv (merged, fused rope/mod/concat epilogue)
  transpose_w<<<dim3(192, 64), dim3(32, 8), 0, stream>>>(txt_qkv_w, wt0, 2048, 6144);
  transpose_w<<<dim3(192, 64), dim3(32, 8), 0, stream>>>(img_qkv_w, wt1, 2048, 6144);
  {
    GemmP p = {actA, wt0, wt1, nullptr, nullptr, nullptr, nullptr,
               rope, modb, q_txt, q_img, k_cat, v_cat, 4, 6144, 2048, 1};
    gemm2<2><<<dim3(48, 20, 1), 256, 0, stream>>>(p);
  }
  transpose_v<<<dim3(80, 4, 16), dim3(32, 8), 0, stream>>>(v_cat, vT);
  // split-KV attention + merge
  attn_kernel<<<dim3(20, 16, 4), 256, 0, stream>>>(q_txt, q_img, k_cat, vT,
                                                   Opart, mlbuf, scales);
  attn_merge<<<5120, 256, 0, stream>>>(Opart, mlbuf, ao);
  // out projection (merged, split-K=2) + residual
  transpose_w<<<dim3(64, 64), dim3(32, 8), 0, stream>>>(txt_out_w, wt0, 2048, 2048);
  transpose_w<<<dim3(64, 64), dim3(32, 8), 0, stream>>>(img_out_w, wt1, 2048, 2048);
  {
    GemmP p = {ao, wt0, wt1, Cbuf, nullptr, nullptr, nullptr,
               nullptr, nullptr, nullptr, nullptr, nullptr, nullptr, 4, 2048, 2048, 2};
    gemm2<0><<<dim3(16, 20, 2), 256, 0, stream>>>(p);
  }
  residual1<<<512, 256, 0, stream>>>((const float4*)txt, (const float4*)Cbuf,
                                     (const float4*)(Cbuf + PSTR), e_txt,
                                     (float4*)out, 512 * 2048 / 4);
  residual1<<<1024, 256, 0, stream>>>((const float4*)img,
                                      (const float4*)(Cbuf + (size_t)512 * 2048),
                                      (const float4*)(Cbuf + PSTR + (size_t)512 * 2048), e_img,
                                      (float4*)out_img, 2048 * 2048 / 4);
  // norm2 -> actA
  rmsmod_kernel<<<512, 256, 0, stream>>>(out, txt_n2_w, e_txt, 6144, 8192, actA);
  rmsmod_kernel<<<2048, 256, 0, stream>>>(out_img, img_n2_w, e_img, 6144, 8192,
                                          actA + (size_t)512 * 2048);
  // fc1 (merged, fused gelu+bias) -> actB bf16 [2560][8192]
  transpose_w<<<dim3(256, 64), dim3(32, 8), 0, stream>>>(txt_fc1_w, wt0, 2048, 8192);
  transpose_w<<<dim3(256, 64), dim3(32, 8), 0, stream>>>(img_fc1_w, wt1, 2048, 8192);
  {
    GemmP p = {actA, wt0, wt1, nullptr, actB, txt_fc1_b, img_fc1_b,
               nullptr, nullptr, nullptr, nullptr, nullptr, nullptr, 4, 8192, 2048, 1};
    gemm2<1><<<dim3(64, 20, 1), 256, 0, stream>>>(p);
  }
  // fc2 (merged, split-K=2) + residual
  transpose_w<<<dim3(64, 256), dim3(32, 8), 0, stream>>>(txt_fc2_w, wt0, 8192, 2048);
  transpose_w<<<dim3(64, 256), dim3(32, 8), 0, stream>>>(img_fc2_w, wt1, 8192, 2048);
  {
    GemmP p = {actB, wt0, wt1, Cbuf, nullptr, nullptr, nullptr,
               nullptr, nullptr, nullptr, nullptr, nullptr, nullptr, 4, 2048, 8192, 2};
    gemm2<0><<<dim3(16, 20, 2), 256, 0, stream>>>(p);
  }
  residual2<<<512, 256, 0, stream>>>((const float4*)Cbuf, (const float4*)(Cbuf + PSTR),
                                     txt_fc2_b, e_txt, (float4*)out, 512 * 2048 / 4);
  residual2<<<1024, 256, 0, stream>>>((const float4*)(Cbuf + (size_t)512 * 2048),
                                      (const float4*)(Cbuf + PSTR + (size_t)512 * 2048),
                                      img_fc2_b, e_img, (float4*)out_img, 2048 * 2048 / 4);
}